// Round 1
// baseline (286.150 us; speedup 1.0000x reference)
//
#include <hip/hip_runtime.h>
#include <hip/hip_bf16.h>

// Sizes (fixed by the problem)
#define NB   16      // batch
#define DT   256     // model dim
#define HT   8       // heads
#define HDT  32      // head dim
#define GP   512     // protein groups (2048/4)
#define GD   128     // drug groups (512/4)

using bf16x8 = __attribute__((ext_vector_type(8))) short;
using f32x4  = __attribute__((ext_vector_type(4))) float;

__device__ __forceinline__ short f2bf(float f) {
  __hip_bfloat16 h = __float2bfloat16(f);
  short s; __builtin_memcpy(&s, &h, 2);
  return s;
}

__device__ __forceinline__ bf16x8 cvt8(float4 a, float4 b) {
  bf16x8 r;
  r[0] = f2bf(a.x); r[1] = f2bf(a.y); r[2] = f2bf(a.z); r[3] = f2bf(a.w);
  r[4] = f2bf(b.x); r[5] = f2bf(b.y); r[6] = f2bf(b.z); r[7] = f2bf(b.w);
  return r;
}

// ---------------- group masks (any over 4) ----------------
extern "C" __global__ void k_masks(const int* __restrict__ mprot, const int* __restrict__ mdrug,
                                   int* __restrict__ mp_g, int* __restrict__ md_g) {
  int t = blockIdx.x * 256 + threadIdx.x;
  if (t < NB * GP) {
    const int* m = mprot + t * 4;
    mp_g[t] = (m[0] | m[1] | m[2] | m[3]) ? 1 : 0;
  } else {
    int u = t - NB * GP;
    if (u < NB * GD) {
      const int* m = mdrug + u * 4;
      md_g[u] = (m[0] | m[1] | m[2] | m[3]) ? 1 : 0;
    }
  }
}

// ---------------- projection: out = group_mean(src) @ W^T ----------------
// Grouping (mean over 4 rows) fused into A-fragment load. One wave computes a
// 16-row x 256-col strip. blockIdx.y selects (Wa,outa)/(Wb,outb).
extern "C" __global__ __launch_bounds__(256)
void k_proj(const float* __restrict__ src, const float* __restrict__ Wa,
            const float* __restrict__ Wb, float* __restrict__ outa,
            float* __restrict__ outb) {
  const float* W   = blockIdx.y ? Wb : Wa;
  float*       out = blockIdx.y ? outb : outa;
  int w = threadIdx.x >> 6, lane = threadIdx.x & 63;
  int c15 = lane & 15, g = lane >> 4;
  int rt = blockIdx.x * 4 + w;          // row tile (16 grouped rows)
  int arow = rt * 16 + c15;             // grouped row for A-fragment
  const float* ap = src + (size_t)arow * 1024;  // 4 source rows of 256

  f32x4 acc[16];
  #pragma unroll
  for (int i = 0; i < 16; ++i) acc[i] = (f32x4){0.f, 0.f, 0.f, 0.f};

  #pragma unroll
  for (int ks = 0; ks < 8; ++ks) {
    int k0 = ks * 32 + g * 8;
    float4 s0  = *(const float4*)(ap + k0);
    float4 s0b = *(const float4*)(ap + k0 + 4);
    float4 s1  = *(const float4*)(ap + 256 + k0);
    float4 s1b = *(const float4*)(ap + 256 + k0 + 4);
    float4 s2  = *(const float4*)(ap + 512 + k0);
    float4 s2b = *(const float4*)(ap + 512 + k0 + 4);
    float4 s3  = *(const float4*)(ap + 768 + k0);
    float4 s3b = *(const float4*)(ap + 768 + k0 + 4);
    float4 av, bv;
    av.x = 0.25f * (s0.x + s1.x + s2.x + s3.x);
    av.y = 0.25f * (s0.y + s1.y + s2.y + s3.y);
    av.z = 0.25f * (s0.z + s1.z + s2.z + s3.z);
    av.w = 0.25f * (s0.w + s1.w + s2.w + s3.w);
    bv.x = 0.25f * (s0b.x + s1b.x + s2b.x + s3b.x);
    bv.y = 0.25f * (s0b.y + s1b.y + s2b.y + s3b.y);
    bv.z = 0.25f * (s0b.z + s1b.z + s2b.z + s3b.z);
    bv.w = 0.25f * (s0b.w + s1b.w + s2b.w + s3b.w);
    bf16x8 af = cvt8(av, bv);
    #pragma unroll
    for (int ct = 0; ct < 16; ++ct) {
      const float* wp = W + (size_t)(ct * 16 + c15) * 256 + k0;
      float4 w0 = *(const float4*)wp;
      float4 w1 = *(const float4*)(wp + 4);
      bf16x8 bfr = cvt8(w0, w1);
      acc[ct] = __builtin_amdgcn_mfma_f32_16x16x32_bf16(af, bfr, acc[ct], 0, 0, 0);
    }
  }
  #pragma unroll
  for (int ct = 0; ct < 16; ++ct) {
    #pragma unroll
    for (int r = 0; r < 4; ++r) {
      out[(size_t)(rt * 16 + 4 * g + r) * 256 + ct * 16 + c15] = acc[ct][r];
    }
  }
}

// ---------------- masked group-mean embedding, stage 1 ----------------
// query_embed shortcut: final col-sums of every sinkhorn map are exactly 1 on
// valid columns, so prot/drug embeddings share numerator
// 0.5*(sum_{mp} vp + sum_{md} vd), divided by cnt_p / cnt_d respectively.
extern "C" __global__ void k_embed_part(const float* __restrict__ vp, const float* __restrict__ vd,
                                        const int* __restrict__ mp_g, const int* __restrict__ md_g,
                                        float* __restrict__ part) {
  int n = blockIdx.x >> 3, s = blockIdx.x & 7, d = threadIdx.x;
  float acc = 0.f;
  for (int j = 0; j < 64; ++j) {
    int gi = s * 64 + j;
    if (mp_g[n * GP + gi]) acc += vp[((size_t)n * GP + gi) * 256 + d];
  }
  for (int j = 0; j < 16; ++j) {
    int gi = s * 16 + j;
    if (md_g[n * GD + gi]) acc += vd[((size_t)n * GD + gi) * 256 + d];
  }
  part[(size_t)blockIdx.x * 256 + d] = acc;
}

// ---------------- embedding, stage 2 ----------------
extern "C" __global__ void k_embed_final(const float* __restrict__ part,
                                         const int* __restrict__ mp_g, const int* __restrict__ md_g,
                                         float* __restrict__ out) {
  int n = blockIdx.x, d = threadIdx.x;
  __shared__ float red[256];
  float cp = (float)(mp_g[n * GP + d] + mp_g[n * GP + 256 + d]);
  float cd = (d < GD) ? (float)md_g[n * GD + d] : 0.f;
  red[d] = cp; __syncthreads();
  for (int st = 128; st > 0; st >>= 1) { if (d < st) red[d] += red[d + st]; __syncthreads(); }
  float cntp = red[0]; __syncthreads();
  red[d] = cd; __syncthreads();
  for (int st = 128; st > 0; st >>= 1) { if (d < st) red[d] += red[d + st]; __syncthreads(); }
  float cntd = red[0]; __syncthreads();
  float numer = 0.f;
  for (int s = 0; s < 8; ++s) numer += part[(size_t)(n * 8 + s) * 256 + d];
  numer *= 0.5f;
  out[n * 512 + d]       = numer / cntp;
  out[n * 512 + 256 + d] = numer / cntd;
}

// ---------------- dp sinkhorn: one block per (n,h), P resident in registers --
// P = exp(logit), A0 = P/Z + 1e-12 (valid), A = diag(r) A0 diag(c).
// row: r <- r/(r*(dot(P_i,c)/Z + 1e-12*Sc) + 1e-12); col symmetric with Sr.
extern "C" __global__ __launch_bounds__(512)
void k4_sinkhorn(const float* __restrict__ qd, const float* __restrict__ kp,
                 const int* __restrict__ md_g, const int* __restrict__ mp_g,
                 float* __restrict__ out) {
  int bid = blockIdx.x;
  // swizzle so all 8 h-blocks of an n land on the same XCD (bid%8)
  int n = ((bid & 7) << 1) | ((bid >> 3) & 1);
  int h = bid >> 4;
  int tid = threadIdx.x;
  int w = tid >> 6, lane = tid & 63;
  int c15 = lane & 15, g = lane >> 4;

  __shared__ float c_s[GP];
  __shared__ float r_s[GD];
  __shared__ float t_s[GD];
  __shared__ float red[8][GP];
  __shared__ float z_sh, sr_sh, sc_sh, kv_sh;
  __shared__ int mp_sh[GP];
  __shared__ int md_sh[GD];

  if (tid < GP) { int m = mp_g[n * GP + tid]; mp_sh[tid] = m; c_s[tid] = m ? 1.f : 0.f; }
  if (tid < GD) { int m = md_g[n * GD + tid]; md_sh[tid] = m; r_s[tid] = m ? 1.f : 0.f; }
  if (tid == 0) z_sh = 0.f;
  __syncthreads();

  if (w == 0) {  // Kv = sum mp
    float v = (float)(mp_sh[lane] + mp_sh[lane + 64] + mp_sh[lane + 128] + mp_sh[lane + 192] +
                      mp_sh[lane + 256] + mp_sh[lane + 320] + mp_sh[lane + 384] + mp_sh[lane + 448]);
    #pragma unroll
    for (int m = 1; m <= 32; m <<= 1) v += __shfl_xor(v, m, 64);
    if (lane == 0) kv_sh = v;
  }

  // ---- logits via MFMA, P in registers: p[ct][r] = P[16w+4g+r][16ct+c15]
  int qrow = 16 * w + c15;
  const float* qp_ = qd + ((size_t)(n * GD + qrow)) * 256 + h * HDT + g * 8;
  float4 q0 = *(const float4*)qp_;
  float4 q1 = *(const float4*)(qp_ + 4);
  bf16x8 af = cvt8(q0, q1);

  float p[32][4];
  #pragma unroll
  for (int ct = 0; ct < 32; ++ct) {
    int krow = 16 * ct + c15;
    const float* kpp = kp + ((size_t)(n * GP + krow)) * 256 + h * HDT + g * 8;
    float4 k0v = *(const float4*)kpp;
    float4 k1v = *(const float4*)(kpp + 4);
    bf16x8 bfr = cvt8(k0v, k1v);
    f32x4 acc = __builtin_amdgcn_mfma_f32_16x16x32_bf16(af, bfr, (f32x4){0.f,0.f,0.f,0.f}, 0, 0, 0);
    int mcol = mp_sh[16 * ct + c15];
    #pragma unroll
    for (int r = 0; r < 4; ++r) {
      int row = 16 * w + 4 * g + r;
      p[ct][r] = (mcol && md_sh[row]) ? __expf(acc[r] * 0.17677669529663687f) : 0.f;
    }
  }

  // ---- initial row sums (c == validity) and Z
  {
    float pa0 = 0.f, pa1 = 0.f, pa2 = 0.f, pa3 = 0.f;
    #pragma unroll
    for (int ct = 0; ct < 32; ++ct) {
      pa0 += p[ct][0]; pa1 += p[ct][1]; pa2 += p[ct][2]; pa3 += p[ct][3];
    }
    #pragma unroll
    for (int m = 1; m <= 8; m <<= 1) {
      pa0 += __shfl_xor(pa0, m, 64); pa1 += __shfl_xor(pa1, m, 64);
      pa2 += __shfl_xor(pa2, m, 64); pa3 += __shfl_xor(pa3, m, 64);
    }
    if (c15 == 0) t_s[16 * w + 4 * g + 0] = pa0;
    if (c15 == 1) t_s[16 * w + 4 * g + 1] = pa1;
    if (c15 == 2) t_s[16 * w + 4 * g + 2] = pa2;
    if (c15 == 3) t_s[16 * w + 4 * g + 3] = pa3;
  }
  __syncthreads();
  if (tid < GD) atomicAdd(&z_sh, t_s[tid]);
  __syncthreads();
  float Zinv = 1.0f / z_sh;
  float Sc = kv_sh;

  #pragma unroll 1
  for (int it = 0; it < 4; ++it) {
    // row update
    if (tid < GD) {
      float ti = t_s[tid] * Zinv + 1e-12f * Sc;
      float ri = r_s[tid];
      r_s[tid] = md_sh[tid] ? (ri / (ri * ti + 1e-12f)) : 0.f;
    }
    __syncthreads();
    if (w == 0) {  // Sr
      float v = r_s[lane] + r_s[lane + 64];
      #pragma unroll
      for (int m = 1; m <= 32; m <<= 1) v += __shfl_xor(v, m, 64);
      if (lane == 0) sr_sh = v;
    }
    __syncthreads();
    float Sr = sr_sh;
    // col pass
    float rr0 = r_s[16 * w + 4 * g + 0];
    float rr1 = r_s[16 * w + 4 * g + 1];
    float rr2 = r_s[16 * w + 4 * g + 2];
    float rr3 = r_s[16 * w + 4 * g + 3];
    #pragma unroll
    for (int ct = 0; ct < 32; ++ct) {
      float u = p[ct][0] * rr0 + p[ct][1] * rr1 + p[ct][2] * rr2 + p[ct][3] * rr3;
      u += __shfl_xor(u, 16, 64);
      u += __shfl_xor(u, 32, 64);
      if (g == 0) red[w][16 * ct + c15] = u;
    }
    __syncthreads();
    // col update
    {
      float cs = red[0][tid] + red[1][tid] + red[2][tid] + red[3][tid] +
                 red[4][tid] + red[5][tid] + red[6][tid] + red[7][tid];
      float uj = cs * Zinv + 1e-12f * Sr;
      float cj = c_s[tid];
      c_s[tid] = mp_sh[tid] ? (cj / (cj * uj + 1e-12f)) : 0.f;
    }
    __syncthreads();
    if (w == 0) {  // Sc
      float v = c_s[lane] + c_s[lane + 64] + c_s[lane + 128] + c_s[lane + 192] +
                c_s[lane + 256] + c_s[lane + 320] + c_s[lane + 384] + c_s[lane + 448];
      #pragma unroll
      for (int m = 1; m <= 32; m <<= 1) v += __shfl_xor(v, m, 64);
      if (lane == 0) sc_sh = v;
    }
    __syncthreads();
    Sc = sc_sh;
    if (it < 3) {  // row pass for next iteration
      float pa0 = 0.f, pa1 = 0.f, pa2 = 0.f, pa3 = 0.f;
      #pragma unroll
      for (int ct = 0; ct < 32; ++ct) {
        float cv = c_s[16 * ct + c15];
        pa0 += p[ct][0] * cv; pa1 += p[ct][1] * cv;
        pa2 += p[ct][2] * cv; pa3 += p[ct][3] * cv;
      }
      #pragma unroll
      for (int m = 1; m <= 8; m <<= 1) {
        pa0 += __shfl_xor(pa0, m, 64); pa1 += __shfl_xor(pa1, m, 64);
        pa2 += __shfl_xor(pa2, m, 64); pa3 += __shfl_xor(pa3, m, 64);
      }
      if (c15 == 0) t_s[16 * w + 4 * g + 0] = pa0;
      if (c15 == 1) t_s[16 * w + 4 * g + 1] = pa1;
      if (c15 == 2) t_s[16 * w + 4 * g + 2] = pa2;
      if (c15 == 3) t_s[16 * w + 4 * g + 3] = pa3;
      __syncthreads();
    }
  }

  // ---- final write: A = r * (P/Z + 1e-12) * c (invalid rows/cols have r/c=0)
  float rrv0 = r_s[16 * w + 4 * g + 0];
  float rrv1 = r_s[16 * w + 4 * g + 1];
  float rrv2 = r_s[16 * w + 4 * g + 2];
  float rrv3 = r_s[16 * w + 4 * g + 3];
  size_t base = 8192 + (size_t)n * (GD * GP * HT) + (size_t)h;
  #pragma unroll
  for (int ct = 0; ct < 32; ++ct) {
    float cc = c_s[16 * ct + c15];
    size_t cb = base + (size_t)(16 * ct + c15) * 8;
    int row = 16 * w + 4 * g;
    out[cb + (size_t)(row + 0) * 4096] = rrv0 * (p[ct][0] * Zinv + 1e-12f) * cc;
    out[cb + (size_t)(row + 1) * 4096] = rrv1 * (p[ct][1] * Zinv + 1e-12f) * cc;
    out[cb + (size_t)(row + 2) * 4096] = rrv2 * (p[ct][2] * Zinv + 1e-12f) * cc;
    out[cb + (size_t)(row + 3) * 4096] = rrv3 * (p[ct][3] * Zinv + 1e-12f) * cc;
  }
}

extern "C" void kernel_launch(void* const* d_in, const int* in_sizes, int n_in,
                              void* d_out, int out_size, void* d_ws, size_t ws_size,
                              hipStream_t stream) {
  const float* protein = (const float*)d_in[0];
  const float* drug    = (const float*)d_in[1];
  const int*   mprot   = (const int*)d_in[2];
  const int*   mdrug   = (const int*)d_in[3];
  // d_in[4] = Wq_p (unused), d_in[8] = Wk_d (unused)
  const float* Wk_p = (const float*)d_in[5];
  const float* Wv_p = (const float*)d_in[6];
  const float* Wq_d = (const float*)d_in[7];
  const float* Wv_d = (const float*)d_in[9];
  float* out = (float*)d_out;

  float* ws   = (float*)d_ws;
  float* vp   = ws;                 // 16*512*256
  float* kp   = vp + 2097152;       // 16*512*256
  float* vd   = kp + 2097152;       // 16*128*256
  float* qd   = vd + 524288;        // 16*128*256
  float* part = qd + 524288;        // 16*8*256
  int*   mp_g = (int*)(part + 32768);  // 16*512
  int*   md_g = mp_g + 8192;           // 16*128

  k_masks<<<40, 256, 0, stream>>>(mprot, mdrug, mp_g, md_g);
  k_proj<<<dim3(128, 2), 256, 0, stream>>>(protein, Wv_p, Wk_p, vp, kp);
  k_proj<<<dim3(32, 2), 256, 0, stream>>>(drug, Wv_d, Wq_d, vd, qd);
  k_embed_part<<<128, 256, 0, stream>>>(vp, vd, mp_g, md_g, part);
  k_embed_final<<<16, 256, 0, stream>>>(part, mp_g, md_g, out);
  k4_sinkhorn<<<128, 512, 0, stream>>>(qd, kp, md_g, mp_g, out);
}

// Round 2
// 222.272 us; speedup vs baseline: 1.2874x; 1.2874x over previous
//
#include <hip/hip_runtime.h>
#include <hip/hip_bf16.h>

// Sizes (fixed by the problem)
#define NB   16      // batch
#define DT   256     // model dim
#define HT   8       // heads
#define HDT  32      // head dim
#define GP   512     // protein groups (2048/4)
#define GD   128     // drug groups (512/4)

using bf16x8 = __attribute__((ext_vector_type(8))) short;
using f32x4  = __attribute__((ext_vector_type(4))) float;

__device__ __forceinline__ short f2bf(float f) {
  __hip_bfloat16 h = __float2bfloat16(f);
  short s; __builtin_memcpy(&s, &h, 2);
  return s;
}

// ---------------- prep: zero sp/sd, convert Wk_p / Wq_d to bf16 -------------
extern "C" __global__ void k_prep(const float* __restrict__ Wk,
                                  const float* __restrict__ Wq,
                                  short* __restrict__ Wk_bf, short* __restrict__ Wq_bf,
                                  float* __restrict__ sp, float* __restrict__ sd) {
  int gid = blockIdx.x * 256 + threadIdx.x;   // grid 512 -> 131072
  if (gid < 65536) Wk_bf[gid] = f2bf(Wk[gid]);
  else             Wq_bf[gid - 65536] = f2bf(Wq[gid - 65536]);
  if (gid < 4096) sp[gid] = 0.f;
  else if (gid < 8192) sd[gid - 4096] = 0.f;
}

// ---------------- grouping: f32 src -> grouped bf16 + masks + masked sums ---
// protein: blocks 0..255 (n = b>>4, 32 groups each); drug: 256..319 (n=(b-256)>>2)
extern "C" __global__ __launch_bounds__(256)
void k_group(const float* __restrict__ protein, const float* __restrict__ drug,
             const int* __restrict__ mprot, const int* __restrict__ mdrug,
             short* __restrict__ pg_bf, short* __restrict__ dg_bf,
             int* __restrict__ mp_g, int* __restrict__ md_g,
             float* __restrict__ sp, float* __restrict__ sd) {
  int b = blockIdx.x;
  int t = threadIdx.x;
  int n, c0, G;
  const float* src; const int* msk; short* dst; float* ssum; int* mg;
  if (b < 256) { n = b >> 4; c0 = (b & 15) * 32; G = GP;
                 src = protein; msk = mprot; dst = pg_bf; ssum = sp; mg = mp_g; }
  else { int bb = b - 256; n = bb >> 2; c0 = (bb & 3) * 32; G = GD;
         src = drug; msk = mdrug; dst = dg_bf; ssum = sd; mg = md_g; }

  __shared__ int gmask[32];
  if (t < 32) {
    const int* m = msk + ((size_t)n * G + c0 + t) * 4;
    int v = (m[0] | m[1] | m[2] | m[3]) ? 1 : 0;
    gmask[t] = v;
    mg[n * G + c0 + t] = v;
  }
  __syncthreads();

  float acc_s = 0.f;
  const float* bp = src + ((size_t)n * G + c0) * 1024 + t;
  #pragma unroll 4
  for (int gi = 0; gi < 32; ++gi) {
    const float* rp = bp + (size_t)gi * 1024;
    float gm = 0.25f * (rp[0] + rp[256] + rp[512] + rp[768]);
    dst[((size_t)n * G + c0 + gi) * 256 + t] = f2bf(gm);
    if (gmask[gi]) acc_s += gm;
  }
  atomicAdd(&ssum[n * 256 + t], acc_s);
}

// ---------------- bf16 projection GEMM: out = A @ W^T (bf16 in, bf16 out) ---
// blocks 0..127: kp = pg_bf @ Wk_bf^T (512 row-tiles); 128..159: qd = dg_bf @ Wq_bf^T
extern "C" __global__ __launch_bounds__(256)
void k_projbf(const short* __restrict__ pg_bf, const short* __restrict__ dg_bf,
              const short* __restrict__ Wk_bf, const short* __restrict__ Wq_bf,
              short* __restrict__ kp_bf, short* __restrict__ qd_bf) {
  int b = blockIdx.x;
  int w = threadIdx.x >> 6, lane = threadIdx.x & 63;
  int c15 = lane & 15, g = lane >> 4;
  const short *A, *W; short* out; int rt;
  if (b < 128) { A = pg_bf; W = Wk_bf; out = kp_bf; rt = b * 4 + w; }
  else         { A = dg_bf; W = Wq_bf; out = qd_bf; rt = (b - 128) * 4 + w; }

  const short* ap = A + ((size_t)rt * 16 + c15) * 256;
  f32x4 acc[16];
  #pragma unroll
  for (int i = 0; i < 16; ++i) acc[i] = (f32x4){0.f, 0.f, 0.f, 0.f};

  #pragma unroll
  for (int ks = 0; ks < 8; ++ks) {
    bf16x8 af = *(const bf16x8*)(ap + ks * 32 + g * 8);
    #pragma unroll
    for (int ct = 0; ct < 16; ++ct) {
      bf16x8 bfr = *(const bf16x8*)(W + ((size_t)(ct * 16 + c15)) * 256 + ks * 32 + g * 8);
      acc[ct] = __builtin_amdgcn_mfma_f32_16x16x32_bf16(af, bfr, acc[ct], 0, 0, 0);
    }
  }
  #pragma unroll
  for (int ct = 0; ct < 16; ++ct) {
    #pragma unroll
    for (int r = 0; r < 4; ++r) {
      out[((size_t)rt * 16 + 4 * g + r) * 256 + ct * 16 + c15] = f2bf(acc[ct][r]);
    }
  }
}

// ---------------- query_embed: 0.5*(sp@Wv_p^T + sd@Wv_d^T)/cnt --------------
extern "C" __global__ __launch_bounds__(256)
void k_embed(const float* __restrict__ sp, const float* __restrict__ sd,
             const float* __restrict__ Wvp, const float* __restrict__ Wvd,
             const int* __restrict__ mp_g, const int* __restrict__ md_g,
             float* __restrict__ out) {
  int n = blockIdx.x, d = threadIdx.x;
  __shared__ float sps[256], sds[256], red[256];
  sps[d] = sp[n * 256 + d];
  sds[d] = sd[n * 256 + d];
  float cp = (float)(mp_g[n * GP + d] + mp_g[n * GP + 256 + d]);
  float cd = (d < GD) ? (float)md_g[n * GD + d] : 0.f;
  red[d] = cp; __syncthreads();
  for (int st = 128; st > 0; st >>= 1) { if (d < st) red[d] += red[d + st]; __syncthreads(); }
  float cntp = red[0]; __syncthreads();
  red[d] = cd; __syncthreads();
  for (int st = 128; st > 0; st >>= 1) { if (d < st) red[d] += red[d + st]; __syncthreads(); }
  float cntd = red[0]; __syncthreads();

  const float* wp = Wvp + (size_t)d * 256;
  const float* wd = Wvd + (size_t)d * 256;
  float acc = 0.f;
  #pragma unroll 4
  for (int k = 0; k < 256; k += 4) {
    float4 a = *(const float4*)(wp + k);
    float4 c = *(const float4*)(wd + k);
    acc += sps[k] * a.x + sps[k + 1] * a.y + sps[k + 2] * a.z + sps[k + 3] * a.w;
    acc += sds[k] * c.x + sds[k + 1] * c.y + sds[k + 2] * c.z + sds[k + 3] * c.w;
  }
  acc *= 0.5f;
  out[n * 512 + d]       = acc / cntp;
  out[n * 512 + 256 + d] = acc / cntd;
}

// ---------------- dp sinkhorn: one block per (n,h), P resident in registers --
// P = exp(logit), A0 = P/Z + 1e-12 (valid), A = diag(r) A0 diag(c).
extern "C" __global__ __launch_bounds__(512, 2)
void k4_sinkhorn(const short* __restrict__ qd, const short* __restrict__ kp,
                 const int* __restrict__ md_g, const int* __restrict__ mp_g,
                 float* __restrict__ out) {
  int bid = blockIdx.x;
  // swizzle so all 8 h-blocks of an n land on the same XCD (bid%8)
  int n = ((bid & 7) << 1) | ((bid >> 3) & 1);
  int h = bid >> 4;
  int tid = threadIdx.x;
  int w = tid >> 6, lane = tid & 63;
  int c15 = lane & 15, g = lane >> 4;

  __shared__ float c_s[GP];
  __shared__ float r_s[GD];
  __shared__ float t_s[GD];
  __shared__ float red[8][GP];
  __shared__ float z_sh, sr_sh, sc_sh, kv_sh;
  __shared__ int mp_sh[GP];
  __shared__ int md_sh[GD];

  if (tid < GP) { int m = mp_g[n * GP + tid]; mp_sh[tid] = m; c_s[tid] = m ? 1.f : 0.f; }
  if (tid < GD) { int m = md_g[n * GD + tid]; md_sh[tid] = m; r_s[tid] = m ? 1.f : 0.f; }
  if (tid == 0) z_sh = 0.f;
  __syncthreads();

  if (w == 0) {  // Kv = sum mp
    float v = (float)(mp_sh[lane] + mp_sh[lane + 64] + mp_sh[lane + 128] + mp_sh[lane + 192] +
                      mp_sh[lane + 256] + mp_sh[lane + 320] + mp_sh[lane + 384] + mp_sh[lane + 448]);
    #pragma unroll
    for (int m = 1; m <= 32; m <<= 1) v += __shfl_xor(v, m, 64);
    if (lane == 0) kv_sh = v;
  }

  // ---- logits via MFMA, P in registers: p[ct][r] = P[16w+4g+r][16ct+c15]
  int qrow = 16 * w + c15;
  bf16x8 af = *(const bf16x8*)(qd + ((size_t)(n * GD + qrow)) * 256 + h * HDT + g * 8);

  float p[32][4];
  #pragma unroll
  for (int ct = 0; ct < 32; ++ct) {
    int krow = 16 * ct + c15;
    bf16x8 bfr = *(const bf16x8*)(kp + ((size_t)(n * GP + krow)) * 256 + h * HDT + g * 8);
    f32x4 acc = __builtin_amdgcn_mfma_f32_16x16x32_bf16(af, bfr, (f32x4){0.f,0.f,0.f,0.f}, 0, 0, 0);
    int mcol = mp_sh[16 * ct + c15];
    #pragma unroll
    for (int r = 0; r < 4; ++r) {
      int row = 16 * w + 4 * g + r;
      p[ct][r] = (mcol && md_sh[row]) ? __expf(acc[r] * 0.17677669529663687f) : 0.f;
    }
  }

  // ---- initial row sums (c == validity) and Z
  {
    float pa0 = 0.f, pa1 = 0.f, pa2 = 0.f, pa3 = 0.f;
    #pragma unroll
    for (int ct = 0; ct < 32; ++ct) {
      pa0 += p[ct][0]; pa1 += p[ct][1]; pa2 += p[ct][2]; pa3 += p[ct][3];
    }
    #pragma unroll
    for (int m = 1; m <= 8; m <<= 1) {
      pa0 += __shfl_xor(pa0, m, 64); pa1 += __shfl_xor(pa1, m, 64);
      pa2 += __shfl_xor(pa2, m, 64); pa3 += __shfl_xor(pa3, m, 64);
    }
    if (c15 == 0) t_s[16 * w + 4 * g + 0] = pa0;
    if (c15 == 1) t_s[16 * w + 4 * g + 1] = pa1;
    if (c15 == 2) t_s[16 * w + 4 * g + 2] = pa2;
    if (c15 == 3) t_s[16 * w + 4 * g + 3] = pa3;
  }
  __syncthreads();
  if (tid < GD) atomicAdd(&z_sh, t_s[tid]);
  __syncthreads();
  float Zinv = 1.0f / z_sh;
  float Sc = kv_sh;

  #pragma unroll 1
  for (int it = 0; it < 4; ++it) {
    // row update
    if (tid < GD) {
      float ti = t_s[tid] * Zinv + 1e-12f * Sc;
      float ri = r_s[tid];
      r_s[tid] = md_sh[tid] ? (ri / (ri * ti + 1e-12f)) : 0.f;
    }
    __syncthreads();
    if (w == 0) {  // Sr
      float v = r_s[lane] + r_s[lane + 64];
      #pragma unroll
      for (int m = 1; m <= 32; m <<= 1) v += __shfl_xor(v, m, 64);
      if (lane == 0) sr_sh = v;
    }
    __syncthreads();
    float Sr = sr_sh;
    // col pass
    float rr0 = r_s[16 * w + 4 * g + 0];
    float rr1 = r_s[16 * w + 4 * g + 1];
    float rr2 = r_s[16 * w + 4 * g + 2];
    float rr3 = r_s[16 * w + 4 * g + 3];
    #pragma unroll
    for (int ct = 0; ct < 32; ++ct) {
      float u = p[ct][0] * rr0 + p[ct][1] * rr1 + p[ct][2] * rr2 + p[ct][3] * rr3;
      u += __shfl_xor(u, 16, 64);
      u += __shfl_xor(u, 32, 64);
      if (g == 0) red[w][16 * ct + c15] = u;
    }
    __syncthreads();
    // col update
    {
      float cs = red[0][tid] + red[1][tid] + red[2][tid] + red[3][tid] +
                 red[4][tid] + red[5][tid] + red[6][tid] + red[7][tid];
      float uj = cs * Zinv + 1e-12f * Sr;
      float cj = c_s[tid];
      c_s[tid] = mp_sh[tid] ? (cj / (cj * uj + 1e-12f)) : 0.f;
    }
    __syncthreads();
    if (w == 0) {  // Sc
      float v = c_s[lane] + c_s[lane + 64] + c_s[lane + 128] + c_s[lane + 192] +
                c_s[lane + 256] + c_s[lane + 320] + c_s[lane + 384] + c_s[lane + 448];
      #pragma unroll
      for (int m = 1; m <= 32; m <<= 1) v += __shfl_xor(v, m, 64);
      if (lane == 0) sc_sh = v;
    }
    __syncthreads();
    Sc = sc_sh;
    if (it < 3) {  // row pass for next iteration
      float pa0 = 0.f, pa1 = 0.f, pa2 = 0.f, pa3 = 0.f;
      #pragma unroll
      for (int ct = 0; ct < 32; ++ct) {
        float cv = c_s[16 * ct + c15];
        pa0 += p[ct][0] * cv; pa1 += p[ct][1] * cv;
        pa2 += p[ct][2] * cv; pa3 += p[ct][3] * cv;
      }
      #pragma unroll
      for (int m = 1; m <= 8; m <<= 1) {
        pa0 += __shfl_xor(pa0, m, 64); pa1 += __shfl_xor(pa1, m, 64);
        pa2 += __shfl_xor(pa2, m, 64); pa3 += __shfl_xor(pa3, m, 64);
      }
      if (c15 == 0) t_s[16 * w + 4 * g + 0] = pa0;
      if (c15 == 1) t_s[16 * w + 4 * g + 1] = pa1;
      if (c15 == 2) t_s[16 * w + 4 * g + 2] = pa2;
      if (c15 == 3) t_s[16 * w + 4 * g + 3] = pa3;
      __syncthreads();
    }
  }

  // ---- final write: A = r * (P/Z + 1e-12) * c (invalid rows/cols have r/c=0)
  float rrv0 = r_s[16 * w + 4 * g + 0];
  float rrv1 = r_s[16 * w + 4 * g + 1];
  float rrv2 = r_s[16 * w + 4 * g + 2];
  float rrv3 = r_s[16 * w + 4 * g + 3];
  size_t base = 8192 + (size_t)n * (GD * GP * HT) + (size_t)h;
  #pragma unroll
  for (int ct = 0; ct < 32; ++ct) {
    float cc = c_s[16 * ct + c15];
    size_t cb = base + (size_t)(16 * ct + c15) * 8;
    int row = 16 * w + 4 * g;
    out[cb + (size_t)(row + 0) * 4096] = rrv0 * (p[ct][0] * Zinv + 1e-12f) * cc;
    out[cb + (size_t)(row + 1) * 4096] = rrv1 * (p[ct][1] * Zinv + 1e-12f) * cc;
    out[cb + (size_t)(row + 2) * 4096] = rrv2 * (p[ct][2] * Zinv + 1e-12f) * cc;
    out[cb + (size_t)(row + 3) * 4096] = rrv3 * (p[ct][3] * Zinv + 1e-12f) * cc;
  }
}

extern "C" void kernel_launch(void* const* d_in, const int* in_sizes, int n_in,
                              void* d_out, int out_size, void* d_ws, size_t ws_size,
                              hipStream_t stream) {
  const float* protein = (const float*)d_in[0];
  const float* drug    = (const float*)d_in[1];
  const int*   mprot   = (const int*)d_in[2];
  const int*   mdrug   = (const int*)d_in[3];
  const float* Wk_p = (const float*)d_in[5];
  const float* Wv_p = (const float*)d_in[6];
  const float* Wq_d = (const float*)d_in[7];
  const float* Wv_d = (const float*)d_in[9];
  float* out = (float*)d_out;

  char* wsb = (char*)d_ws;
  short* pg_bf = (short*)wsb;                 wsb += (size_t)NB * GP * 256 * 2;  // 4 MB
  short* dg_bf = (short*)wsb;                 wsb += (size_t)NB * GD * 256 * 2;  // 1 MB
  short* kp_bf = (short*)wsb;                 wsb += (size_t)NB * GP * 256 * 2;  // 4 MB
  short* qd_bf = (short*)wsb;                 wsb += (size_t)NB * GD * 256 * 2;  // 1 MB
  short* Wk_bf = (short*)wsb;                 wsb += 65536 * 2;
  short* Wq_bf = (short*)wsb;                 wsb += 65536 * 2;
  float* sp    = (float*)wsb;                 wsb += 4096 * 4;
  float* sd    = (float*)wsb;                 wsb += 4096 * 4;
  int*   mp_g  = (int*)wsb;                   wsb += 8192 * 4;
  int*   md_g  = (int*)wsb;                   wsb += 2048 * 4;

  k_prep<<<512, 256, 0, stream>>>(Wk_p, Wq_d, Wk_bf, Wq_bf, sp, sd);
  k_group<<<320, 256, 0, stream>>>(protein, drug, mprot, mdrug,
                                   pg_bf, dg_bf, mp_g, md_g, sp, sd);
  k_projbf<<<160, 256, 0, stream>>>(pg_bf, dg_bf, Wk_bf, Wq_bf, kp_bf, qd_bf);
  k_embed<<<16, 256, 0, stream>>>(sp, sd, Wv_p, Wv_d, mp_g, md_g, out);
  k4_sinkhorn<<<128, 512, 0, stream>>>(qd_bf, kp_bf, md_g, mp_g, out);
}

// Round 3
// 194.289 us; speedup vs baseline: 1.4728x; 1.1440x over previous
//
#include <hip/hip_runtime.h>
#include <hip/hip_bf16.h>

// Sizes (fixed by the problem)
#define NB   16      // batch
#define DT   256     // model dim
#define HT   8       // heads
#define HDT  32      // head dim
#define GP   512     // protein groups (2048/4)
#define GD   128     // drug groups (512/4)

using bf16x8 = __attribute__((ext_vector_type(8))) short;
using f32x4  = __attribute__((ext_vector_type(4))) float;

__device__ __forceinline__ short f2bf(float f) {
  __hip_bfloat16 h = __float2bfloat16(f);
  short s; __builtin_memcpy(&s, &h, 2);
  return s;
}

// ---------------- prep: zero sp/sd/cnt, convert Wk_p / Wq_d to bf16 ---------
extern "C" __global__ void k_prep(const float* __restrict__ Wk,
                                  const float* __restrict__ Wq,
                                  short* __restrict__ Wk_bf, short* __restrict__ Wq_bf,
                                  float* __restrict__ sp, float* __restrict__ sd,
                                  int* __restrict__ cnt) {
  int gid = blockIdx.x * 256 + threadIdx.x;   // grid 512 -> 131072
  if (gid < 65536) Wk_bf[gid] = f2bf(Wk[gid]);
  else             Wq_bf[gid - 65536] = f2bf(Wq[gid - 65536]);
  if (gid < 4096) sp[gid] = 0.f;
  else if (gid < 8192) sd[gid - 4096] = 0.f;
  if (gid < 32) cnt[gid] = 0;
}

// ---------------- grouping: f32 src -> grouped bf16 + masks + sums + counts -
// protein: blocks 0..255 (n = b>>4, 32 groups each); drug: 256..319 (n=(b-256)>>2)
extern "C" __global__ __launch_bounds__(256)
void k_group(const float* __restrict__ protein, const float* __restrict__ drug,
             const int* __restrict__ mprot, const int* __restrict__ mdrug,
             short* __restrict__ pg_bf, short* __restrict__ dg_bf,
             int* __restrict__ mp_g, int* __restrict__ md_g,
             float* __restrict__ sp, float* __restrict__ sd,
             int* __restrict__ cnt) {
  int b = blockIdx.x;
  int t = threadIdx.x;
  int n, c0, G;
  const float* src; const int* msk; short* dst; float* ssum; int* mg; int* cdst;
  if (b < 256) { n = b >> 4; c0 = (b & 15) * 32; G = GP;
                 src = protein; msk = mprot; dst = pg_bf; ssum = sp; mg = mp_g;
                 cdst = cnt + n; }
  else { int bb = b - 256; n = bb >> 2; c0 = (bb & 3) * 32; G = GD;
         src = drug; msk = mdrug; dst = dg_bf; ssum = sd; mg = md_g;
         cdst = cnt + 16 + n; }

  __shared__ int gmask[32];
  if (t < 32) {
    const int* m = msk + ((size_t)n * G + c0 + t) * 4;
    int v = (m[0] | m[1] | m[2] | m[3]) ? 1 : 0;
    gmask[t] = v;
    mg[n * G + c0 + t] = v;
  }
  __syncthreads();
  if (t == 0) {
    int c = 0;
    #pragma unroll
    for (int i = 0; i < 32; ++i) c += gmask[i];
    atomicAdd(cdst, c);
  }

  float acc_s = 0.f;
  const float* bp = src + ((size_t)n * G + c0) * 1024 + t;
  #pragma unroll 4
  for (int gi = 0; gi < 32; ++gi) {
    const float* rp = bp + (size_t)gi * 1024;
    float gm = 0.25f * (rp[0] + rp[256] + rp[512] + rp[768]);
    dst[((size_t)n * G + c0 + gi) * 256 + t] = f2bf(gm);
    if (gmask[gi]) acc_s += gm;
  }
  atomicAdd(&ssum[n * 256 + t], acc_s);
}

// ---------------- bf16 projection GEMM: out = A @ W^T (bf16 in, bf16 out) ---
extern "C" __global__ __launch_bounds__(256)
void k_projbf(const short* __restrict__ pg_bf, const short* __restrict__ dg_bf,
              const short* __restrict__ Wk_bf, const short* __restrict__ Wq_bf,
              short* __restrict__ kp_bf, short* __restrict__ qd_bf) {
  int b = blockIdx.x;
  int w = threadIdx.x >> 6, lane = threadIdx.x & 63;
  int c15 = lane & 15, g = lane >> 4;
  const short *A, *W; short* out; int rt;
  if (b < 128) { A = pg_bf; W = Wk_bf; out = kp_bf; rt = b * 4 + w; }
  else         { A = dg_bf; W = Wq_bf; out = qd_bf; rt = (b - 128) * 4 + w; }

  const short* ap = A + ((size_t)rt * 16 + c15) * 256;
  f32x4 acc[16];
  #pragma unroll
  for (int i = 0; i < 16; ++i) acc[i] = (f32x4){0.f, 0.f, 0.f, 0.f};

  #pragma unroll
  for (int ks = 0; ks < 8; ++ks) {
    bf16x8 af = *(const bf16x8*)(ap + ks * 32 + g * 8);
    #pragma unroll
    for (int ct = 0; ct < 16; ++ct) {
      bf16x8 bfr = *(const bf16x8*)(W + ((size_t)(ct * 16 + c15)) * 256 + ks * 32 + g * 8);
      acc[ct] = __builtin_amdgcn_mfma_f32_16x16x32_bf16(af, bfr, acc[ct], 0, 0, 0);
    }
  }
  #pragma unroll
  for (int ct = 0; ct < 16; ++ct) {
    #pragma unroll
    for (int r = 0; r < 4; ++r) {
      out[((size_t)rt * 16 + 4 * g + r) * 256 + ct * 16 + c15] = f2bf(acc[ct][r]);
    }
  }
}

// ---------------- query_embed: 0.5*(sp@Wv_p^T + sd@Wv_d^T)/cnt --------------
// grid 128: n = b>>3, d-chunk of 32; 8 lanes per output col, shfl-reduced.
extern "C" __global__ __launch_bounds__(256)
void k_embed(const float* __restrict__ sp, const float* __restrict__ sd,
             const float* __restrict__ Wvp, const float* __restrict__ Wvd,
             const int* __restrict__ cnt, float* __restrict__ out) {
  int n = blockIdx.x >> 3;
  int dchunk = (blockIdx.x & 7) * 32;
  int t = threadIdx.x;
  __shared__ float sps[256], sds[256];
  sps[t] = sp[n * 256 + t];
  sds[t] = sd[n * 256 + t];
  __syncthreads();
  int dloc = t >> 3, ks = (t & 7) * 32;
  int d = dchunk + dloc;
  const float* wp = Wvp + (size_t)d * 256 + ks;
  const float* wd = Wvd + (size_t)d * 256 + ks;
  float acc = 0.f;
  #pragma unroll
  for (int k = 0; k < 32; k += 4) {
    float4 a = *(const float4*)(wp + k);
    float4 c = *(const float4*)(wd + k);
    acc += sps[ks + k] * a.x + sps[ks + k + 1] * a.y + sps[ks + k + 2] * a.z + sps[ks + k + 3] * a.w
         + sds[ks + k] * c.x + sds[ks + k + 1] * c.y + sds[ks + k + 2] * c.z + sds[ks + k + 3] * c.w;
  }
  #pragma unroll
  for (int m = 1; m <= 4; m <<= 1) acc += __shfl_xor(acc, m, 64);
  if ((t & 7) == 0) {
    acc *= 0.5f;
    out[n * 512 + d]       = acc / (float)cnt[n];
    out[n * 512 + 256 + d] = acc / (float)cnt[16 + n];
  }
}

// ---------------- dp sinkhorn scalars: one block per (n,h), P in registers --
// Outputs only r[128], c[512], Zinv per (n,h) into rcz (stride 1024 floats).
extern "C" __global__ __launch_bounds__(512, 2)
void k_scalars(const short* __restrict__ qd, const short* __restrict__ kp,
               const int* __restrict__ md_g, const int* __restrict__ mp_g,
               float* __restrict__ rcz) {
  int bid = blockIdx.x;
  int n = ((bid & 7) << 1) | ((bid >> 3) & 1);
  int h = bid >> 4;
  int tid = threadIdx.x;
  int w = tid >> 6, lane = tid & 63;
  int c15 = lane & 15, g = lane >> 4;

  __shared__ float c_s[GP];
  __shared__ float r_s[GD];
  __shared__ float t_s[GD];
  __shared__ float red[8][GP];
  __shared__ float z_sh, sr_sh, sc_sh, kv_sh;
  __shared__ int mp_sh[GP];
  __shared__ int md_sh[GD];

  if (tid < GP) { int m = mp_g[n * GP + tid]; mp_sh[tid] = m; c_s[tid] = m ? 1.f : 0.f; }
  if (tid < GD) { int m = md_g[n * GD + tid]; md_sh[tid] = m; r_s[tid] = m ? 1.f : 0.f; }
  if (tid == 0) z_sh = 0.f;
  __syncthreads();

  if (w == 0) {  // Kv = sum mp
    float v = (float)(mp_sh[lane] + mp_sh[lane + 64] + mp_sh[lane + 128] + mp_sh[lane + 192] +
                      mp_sh[lane + 256] + mp_sh[lane + 320] + mp_sh[lane + 384] + mp_sh[lane + 448]);
    #pragma unroll
    for (int m = 1; m <= 32; m <<= 1) v += __shfl_xor(v, m, 64);
    if (lane == 0) kv_sh = v;
  }

  // ---- logits via MFMA, P in registers: p[ct][r] = P[16w+4g+r][16ct+c15]
  int qrow = 16 * w + c15;
  bf16x8 af = *(const bf16x8*)(qd + ((size_t)(n * GD + qrow)) * 256 + h * HDT + g * 8);

  float p[32][4];
  #pragma unroll
  for (int ct = 0; ct < 32; ++ct) {
    int krow = 16 * ct + c15;
    bf16x8 bfr = *(const bf16x8*)(kp + ((size_t)(n * GP + krow)) * 256 + h * HDT + g * 8);
    f32x4 acc = __builtin_amdgcn_mfma_f32_16x16x32_bf16(af, bfr, (f32x4){0.f,0.f,0.f,0.f}, 0, 0, 0);
    int mcol = mp_sh[16 * ct + c15];
    #pragma unroll
    for (int r = 0; r < 4; ++r) {
      int row = 16 * w + 4 * g + r;
      p[ct][r] = (mcol && md_sh[row]) ? __expf(acc[r] * 0.17677669529663687f) : 0.f;
    }
  }

  // ---- initial row sums (c == validity) and Z
  {
    float pa0 = 0.f, pa1 = 0.f, pa2 = 0.f, pa3 = 0.f;
    #pragma unroll
    for (int ct = 0; ct < 32; ++ct) {
      pa0 += p[ct][0]; pa1 += p[ct][1]; pa2 += p[ct][2]; pa3 += p[ct][3];
    }
    #pragma unroll
    for (int m = 1; m <= 8; m <<= 1) {
      pa0 += __shfl_xor(pa0, m, 64); pa1 += __shfl_xor(pa1, m, 64);
      pa2 += __shfl_xor(pa2, m, 64); pa3 += __shfl_xor(pa3, m, 64);
    }
    if (c15 == 0) t_s[16 * w + 4 * g + 0] = pa0;
    if (c15 == 1) t_s[16 * w + 4 * g + 1] = pa1;
    if (c15 == 2) t_s[16 * w + 4 * g + 2] = pa2;
    if (c15 == 3) t_s[16 * w + 4 * g + 3] = pa3;
  }
  __syncthreads();
  if (tid < GD) atomicAdd(&z_sh, t_s[tid]);
  __syncthreads();
  float Zinv = 1.0f / z_sh;
  float Sc = kv_sh;

  #pragma unroll 1
  for (int it = 0; it < 4; ++it) {
    // row update
    if (tid < GD) {
      float ti = t_s[tid] * Zinv + 1e-12f * Sc;
      float ri = r_s[tid];
      r_s[tid] = md_sh[tid] ? (ri / (ri * ti + 1e-12f)) : 0.f;
    }
    __syncthreads();
    if (w == 0) {  // Sr
      float v = r_s[lane] + r_s[lane + 64];
      #pragma unroll
      for (int m = 1; m <= 32; m <<= 1) v += __shfl_xor(v, m, 64);
      if (lane == 0) sr_sh = v;
    }
    __syncthreads();
    float Sr = sr_sh;
    // col pass
    float rr0 = r_s[16 * w + 4 * g + 0];
    float rr1 = r_s[16 * w + 4 * g + 1];
    float rr2 = r_s[16 * w + 4 * g + 2];
    float rr3 = r_s[16 * w + 4 * g + 3];
    #pragma unroll
    for (int ct = 0; ct < 32; ++ct) {
      float u = p[ct][0] * rr0 + p[ct][1] * rr1 + p[ct][2] * rr2 + p[ct][3] * rr3;
      u += __shfl_xor(u, 16, 64);
      u += __shfl_xor(u, 32, 64);
      if (g == 0) red[w][16 * ct + c15] = u;
    }
    __syncthreads();
    // col update
    {
      float cs = red[0][tid] + red[1][tid] + red[2][tid] + red[3][tid] +
                 red[4][tid] + red[5][tid] + red[6][tid] + red[7][tid];
      float uj = cs * Zinv + 1e-12f * Sr;
      float cj = c_s[tid];
      c_s[tid] = mp_sh[tid] ? (cj / (cj * uj + 1e-12f)) : 0.f;
    }
    __syncthreads();
    if (w == 0) {  // Sc
      float v = c_s[lane] + c_s[lane + 64] + c_s[lane + 128] + c_s[lane + 192] +
                c_s[lane + 256] + c_s[lane + 320] + c_s[lane + 384] + c_s[lane + 448];
      #pragma unroll
      for (int m = 1; m <= 32; m <<= 1) v += __shfl_xor(v, m, 64);
      if (lane == 0) sc_sh = v;
    }
    __syncthreads();
    Sc = sc_sh;
    if (it < 3) {  // row pass for next iteration
      float pa0 = 0.f, pa1 = 0.f, pa2 = 0.f, pa3 = 0.f;
      #pragma unroll
      for (int ct = 0; ct < 32; ++ct) {
        float cv = c_s[16 * ct + c15];
        pa0 += p[ct][0] * cv; pa1 += p[ct][1] * cv;
        pa2 += p[ct][2] * cv; pa3 += p[ct][3] * cv;
      }
      #pragma unroll
      for (int m = 1; m <= 8; m <<= 1) {
        pa0 += __shfl_xor(pa0, m, 64); pa1 += __shfl_xor(pa1, m, 64);
        pa2 += __shfl_xor(pa2, m, 64); pa3 += __shfl_xor(pa3, m, 64);
      }
      if (c15 == 0) t_s[16 * w + 4 * g + 0] = pa0;
      if (c15 == 1) t_s[16 * w + 4 * g + 1] = pa1;
      if (c15 == 2) t_s[16 * w + 4 * g + 2] = pa2;
      if (c15 == 3) t_s[16 * w + 4 * g + 3] = pa3;
      __syncthreads();
    }
  }

  // ---- tiny output: r, c, Zinv
  size_t rb = (size_t)(n * 8 + h) * 1024;
  if (tid < GD) rcz[rb + tid] = r_s[tid];
  if (tid < GP) rcz[rb + 128 + tid] = c_s[tid];
  if (tid == 0) rcz[rb + 640] = Zinv;
}

// ---------------- A writer: recompute P, apply r/c/Zinv, coalesced h-stores -
// grid 512: xcd=bid&7 -> n=(xcd<<1)|(bid>>3&1); rest=bid>>4 = rt*4+cc.
// Block covers (n, 16 drug rows, 128 prot cols); wave w -> 32 cols; h inner so
// each lane holds the 8 h-values of its cell -> two float4 stores (32B contig).
extern "C" __global__ __launch_bounds__(256)
void k_write(const short* __restrict__ qd, const short* __restrict__ kp,
             const float* __restrict__ rcz, float* __restrict__ out) {
  int bid = blockIdx.x;
  int n = ((bid & 7) << 1) | ((bid >> 3) & 1);
  int rest = bid >> 4;
  int rt = rest >> 2;            // row tile (16 rows)
  int cc = rest & 3;             // col chunk (128 cols)
  int w = threadIdx.x >> 6, lane = threadIdx.x & 63;
  int c15 = lane & 15, g = lane >> 4;

  const short* qbase = qd + ((size_t)(n * GD + rt * 16 + c15)) * 256;
  bf16x8 af[8];
  #pragma unroll
  for (int h = 0; h < 8; ++h) af[h] = *(const bf16x8*)(qbase + h * HDT + g * 8);

  size_t rb = (size_t)n * 8 * 1024;
  float rv[8][4], zin[8];
  #pragma unroll
  for (int h = 0; h < 8; ++h) {
    const float* rp = rcz + rb + (size_t)h * 1024;
    #pragma unroll
    for (int r = 0; r < 4; ++r) rv[h][r] = rp[rt * 16 + 4 * g + r];
    zin[h] = rp[640];
  }

  #pragma unroll
  for (int ct = 0; ct < 2; ++ct) {
    int col = cc * 128 + w * 32 + ct * 16 + c15;
    f32x4 acc[8]; float cw[8];
    #pragma unroll
    for (int h = 0; h < 8; ++h) {
      bf16x8 bfr = *(const bf16x8*)(kp + ((size_t)(n * GP + col)) * 256 + h * HDT + g * 8);
      acc[h] = __builtin_amdgcn_mfma_f32_16x16x32_bf16(af[h], bfr, (f32x4){0.f,0.f,0.f,0.f}, 0, 0, 0);
      cw[h] = rcz[rb + (size_t)h * 1024 + 128 + col];
    }
    #pragma unroll
    for (int r = 0; r < 4; ++r) {
      int row = rt * 16 + 4 * g + r;
      float4 lo, hi;
      lo.x = rv[0][r] * (__expf(acc[0][r] * 0.17677669529663687f) * zin[0] + 1e-12f) * cw[0];
      lo.y = rv[1][r] * (__expf(acc[1][r] * 0.17677669529663687f) * zin[1] + 1e-12f) * cw[1];
      lo.z = rv[2][r] * (__expf(acc[2][r] * 0.17677669529663687f) * zin[2] + 1e-12f) * cw[2];
      lo.w = rv[3][r] * (__expf(acc[3][r] * 0.17677669529663687f) * zin[3] + 1e-12f) * cw[3];
      hi.x = rv[4][r] * (__expf(acc[4][r] * 0.17677669529663687f) * zin[4] + 1e-12f) * cw[4];
      hi.y = rv[5][r] * (__expf(acc[5][r] * 0.17677669529663687f) * zin[5] + 1e-12f) * cw[5];
      hi.z = rv[6][r] * (__expf(acc[6][r] * 0.17677669529663687f) * zin[6] + 1e-12f) * cw[6];
      hi.w = rv[7][r] * (__expf(acc[7][r] * 0.17677669529663687f) * zin[7] + 1e-12f) * cw[7];
      float* dst = out + 8192 + (((size_t)(n * GD + row)) * GP + col) * 8;
      *(float4*)dst = lo;
      *(float4*)(dst + 4) = hi;
    }
  }
}

extern "C" void kernel_launch(void* const* d_in, const int* in_sizes, int n_in,
                              void* d_out, int out_size, void* d_ws, size_t ws_size,
                              hipStream_t stream) {
  const float* protein = (const float*)d_in[0];
  const float* drug    = (const float*)d_in[1];
  const int*   mprot   = (const int*)d_in[2];
  const int*   mdrug   = (const int*)d_in[3];
  const float* Wk_p = (const float*)d_in[5];
  const float* Wv_p = (const float*)d_in[6];
  const float* Wq_d = (const float*)d_in[7];
  const float* Wv_d = (const float*)d_in[9];
  float* out = (float*)d_out;

  char* wsb = (char*)d_ws;
  short* pg_bf = (short*)wsb;                 wsb += (size_t)NB * GP * 256 * 2;  // 4 MB
  short* dg_bf = (short*)wsb;                 wsb += (size_t)NB * GD * 256 * 2;  // 1 MB
  short* kp_bf = (short*)wsb;                 wsb += (size_t)NB * GP * 256 * 2;  // 4 MB
  short* qd_bf = (short*)wsb;                 wsb += (size_t)NB * GD * 256 * 2;  // 1 MB
  short* Wk_bf = (short*)wsb;                 wsb += 65536 * 2;
  short* Wq_bf = (short*)wsb;                 wsb += 65536 * 2;
  float* sp    = (float*)wsb;                 wsb += 4096 * 4;
  float* sd    = (float*)wsb;                 wsb += 4096 * 4;
  float* rcz   = (float*)wsb;                 wsb += (size_t)128 * 1024 * 4;     // 512 KB
  int*   cnt   = (int*)wsb;                   wsb += 32 * 4;
  int*   mp_g  = (int*)wsb;                   wsb += 8192 * 4;
  int*   md_g  = (int*)wsb;                   wsb += 2048 * 4;

  k_prep<<<512, 256, 0, stream>>>(Wk_p, Wq_d, Wk_bf, Wq_bf, sp, sd, cnt);
  k_group<<<320, 256, 0, stream>>>(protein, drug, mprot, mdrug,
                                   pg_bf, dg_bf, mp_g, md_g, sp, sd, cnt);
  k_projbf<<<160, 256, 0, stream>>>(pg_bf, dg_bf, Wk_bf, Wq_bf, kp_bf, qd_bf);
  k_embed<<<128, 256, 0, stream>>>(sp, sd, Wv_p, Wv_d, cnt, out);
  k_scalars<<<128, 512, 0, stream>>>(qd_bf, kp_bf, md_g, mp_g, rcz);
  k_write<<<512, 256, 0, stream>>>(qd_bf, kp_bf, rcz, out);
}

// Round 4
// 186.750 us; speedup vs baseline: 1.5323x; 1.0404x over previous
//
#include <hip/hip_runtime.h>
#include <hip/hip_bf16.h>

// Sizes (fixed by the problem)
#define NB   16      // batch
#define DT   256     // model dim
#define HT   8       // heads
#define HDT  32      // head dim
#define GP   512     // protein groups (2048/4)
#define GD   128     // drug groups (512/4)

using bf16x8 = __attribute__((ext_vector_type(8))) short;
using f32x4  = __attribute__((ext_vector_type(4))) float;

__device__ __forceinline__ short f2bf(float f) {
  __hip_bfloat16 h = __float2bfloat16(f);
  short s; __builtin_memcpy(&s, &h, 2);
  return s;
}

// ---------------- grouping + W cvt, partial sums (no atomics, no pre-zero) --
// blocks 0..255: protein (n=b>>4, 32 groups); 256..319: drug (n=(b-256)>>2);
// 320..575: convert Wk_p/Wq_d to bf16 (512 elems per block).
extern "C" __global__ __launch_bounds__(256)
void k_group(const float* __restrict__ protein, const float* __restrict__ drug,
             const int* __restrict__ mprot, const int* __restrict__ mdrug,
             const float* __restrict__ Wk, const float* __restrict__ Wq,
             short* __restrict__ pg_bf, short* __restrict__ dg_bf,
             int* __restrict__ mp_g, int* __restrict__ md_g,
             short* __restrict__ Wk_bf, short* __restrict__ Wq_bf,
             float* __restrict__ part, int* __restrict__ cntp) {
  int b = blockIdx.x;
  int t = threadIdx.x;
  if (b >= 320) {  // W conversion
    int base = (b - 320) * 512;
    #pragma unroll
    for (int j = 0; j < 2; ++j) {
      int gid = base + t + j * 256;
      if (gid < 65536) Wk_bf[gid] = f2bf(Wk[gid]);
      else             Wq_bf[gid - 65536] = f2bf(Wq[gid - 65536]);
    }
    return;
  }
  int n, c0, G;
  const float* src; const int* msk; short* dst; int* mg;
  if (b < 256) { n = b >> 4; c0 = (b & 15) * 32; G = GP;
                 src = protein; msk = mprot; dst = pg_bf; mg = mp_g; }
  else { int bb = b - 256; n = bb >> 2; c0 = (bb & 3) * 32; G = GD;
         src = drug; msk = mdrug; dst = dg_bf; mg = md_g; }

  __shared__ int gmask[32];
  if (t < 32) {
    const int* m = msk + ((size_t)n * G + c0 + t) * 4;
    int v = (m[0] | m[1] | m[2] | m[3]) ? 1 : 0;
    gmask[t] = v;
    mg[n * G + c0 + t] = v;
  }
  __syncthreads();
  if (t == 0) {
    int c = 0;
    #pragma unroll
    for (int i = 0; i < 32; ++i) c += gmask[i];
    cntp[b] = c;
  }

  float acc_s = 0.f;
  const float* bp = src + ((size_t)n * G + c0) * 1024 + t;
  #pragma unroll 4
  for (int gi = 0; gi < 32; ++gi) {
    const float* rp = bp + (size_t)gi * 1024;
    float gm = 0.25f * (rp[0] + rp[256] + rp[512] + rp[768]);
    dst[((size_t)n * G + c0 + gi) * 256 + t] = f2bf(gm);
    if (gmask[gi]) acc_s += gm;
  }
  part[(size_t)b * 256 + t] = acc_s;
}

// ---------------- projection GEMM + fused query_embed -----------------------
// blocks 0..127: kp = pg@Wk^T; 128..159: qd = dg@Wq^T; 160..287: embed.
extern "C" __global__ __launch_bounds__(256)
void k_proj_embed(const short* __restrict__ pg_bf, const short* __restrict__ dg_bf,
                  const short* __restrict__ Wk_bf, const short* __restrict__ Wq_bf,
                  short* __restrict__ kp_bf, short* __restrict__ qd_bf,
                  const float* __restrict__ part, const int* __restrict__ cntp,
                  const float* __restrict__ Wvp, const float* __restrict__ Wvd,
                  float* __restrict__ out) {
  int b = blockIdx.x;
  int t = threadIdx.x;
  if (b >= 160) {  // ---- embed: 0.5*(sp@Wvp^T + sd@Wvd^T)/cnt ----
    int bb = b - 160;
    int n = bb >> 3;
    int dchunk = (bb & 7) * 32;
    __shared__ float sps[256], sds[256];
    float a1 = 0.f;
    #pragma unroll
    for (int i = 0; i < 16; ++i) a1 += part[(size_t)(n * 16 + i) * 256 + t];
    sps[t] = a1;
    float a2 = 0.f;
    #pragma unroll
    for (int i = 0; i < 4; ++i) a2 += part[(size_t)(256 + n * 4 + i) * 256 + t];
    sds[t] = a2;
    __syncthreads();
    int cp = 0, cd = 0;
    #pragma unroll
    for (int i = 0; i < 16; ++i) cp += cntp[n * 16 + i];
    #pragma unroll
    for (int i = 0; i < 4; ++i) cd += cntp[256 + n * 4 + i];
    int dloc = t >> 3, ks = (t & 7) * 32;
    int d = dchunk + dloc;
    const float* wp = Wvp + (size_t)d * 256 + ks;
    const float* wd = Wvd + (size_t)d * 256 + ks;
    float acc = 0.f;
    #pragma unroll
    for (int k = 0; k < 32; k += 4) {
      float4 a = *(const float4*)(wp + k);
      float4 c = *(const float4*)(wd + k);
      acc += sps[ks + k] * a.x + sps[ks + k + 1] * a.y + sps[ks + k + 2] * a.z + sps[ks + k + 3] * a.w
           + sds[ks + k] * c.x + sds[ks + k + 1] * c.y + sds[ks + k + 2] * c.z + sds[ks + k + 3] * c.w;
    }
    #pragma unroll
    for (int m = 1; m <= 4; m <<= 1) acc += __shfl_xor(acc, m, 64);
    if ((t & 7) == 0) {
      acc *= 0.5f;
      out[n * 512 + d]       = acc / (float)cp;
      out[n * 512 + 256 + d] = acc / (float)cd;
    }
    return;
  }
  // ---- projection ----
  int w = t >> 6, lane = t & 63;
  int c15 = lane & 15, g = lane >> 4;
  const short *A, *W; short* o; int rt;
  if (b < 128) { A = pg_bf; W = Wk_bf; o = kp_bf; rt = b * 4 + w; }
  else         { A = dg_bf; W = Wq_bf; o = qd_bf; rt = (b - 128) * 4 + w; }

  const short* ap = A + ((size_t)rt * 16 + c15) * 256;
  f32x4 acc[16];
  #pragma unroll
  for (int i = 0; i < 16; ++i) acc[i] = (f32x4){0.f, 0.f, 0.f, 0.f};

  #pragma unroll
  for (int ks = 0; ks < 8; ++ks) {
    bf16x8 af = *(const bf16x8*)(ap + ks * 32 + g * 8);
    #pragma unroll
    for (int ct = 0; ct < 16; ++ct) {
      bf16x8 bfr = *(const bf16x8*)(W + ((size_t)(ct * 16 + c15)) * 256 + ks * 32 + g * 8);
      acc[ct] = __builtin_amdgcn_mfma_f32_16x16x32_bf16(af, bfr, acc[ct], 0, 0, 0);
    }
  }
  #pragma unroll
  for (int ct = 0; ct < 16; ++ct) {
    #pragma unroll
    for (int r = 0; r < 4; ++r) {
      o[((size_t)rt * 16 + 4 * g + r) * 256 + ct * 16 + c15] = f2bf(acc[ct][r]);
    }
  }
}

// ---------------- dp sinkhorn scalars: one block per (n,h) ------------------
// P kept in f16 (64 packed VGPRs) to avoid scratch spill; all arithmetic f32.
// Outputs r[128], c[512], Zinv per (n,h) into rcz (stride 1024 floats).
extern "C" __global__ __launch_bounds__(512)
void k_scalars(const short* __restrict__ qd, const short* __restrict__ kp,
               const int* __restrict__ md_g, const int* __restrict__ mp_g,
               float* __restrict__ rcz) {
  int bid = blockIdx.x;
  int n = ((bid & 7) << 1) | ((bid >> 3) & 1);
  int h = bid >> 4;
  int tid = threadIdx.x;
  int w = tid >> 6, lane = tid & 63;
  int c15 = lane & 15, g = lane >> 4;

  __shared__ float c_s[GP];
  __shared__ float r_s[GD];
  __shared__ float t_s[GD];
  __shared__ float red[8][GP];
  __shared__ float z_sh, sr_sh, sc_sh, kv_sh;
  __shared__ int mp_sh[GP];
  __shared__ int md_sh[GD];

  if (tid < GP) { int m = mp_g[n * GP + tid]; mp_sh[tid] = m; c_s[tid] = m ? 1.f : 0.f; }
  if (tid < GD) { int m = md_g[n * GD + tid]; md_sh[tid] = m; r_s[tid] = m ? 1.f : 0.f; }
  __syncthreads();

  if (w == 0) {  // Kv = sum mp
    float v = (float)(mp_sh[lane] + mp_sh[lane + 64] + mp_sh[lane + 128] + mp_sh[lane + 192] +
                      mp_sh[lane + 256] + mp_sh[lane + 320] + mp_sh[lane + 384] + mp_sh[lane + 448]);
    #pragma unroll
    for (int m = 1; m <= 32; m <<= 1) v += __shfl_xor(v, m, 64);
    if (lane == 0) kv_sh = v;
  }

  // ---- logits via MFMA, P (f16) in registers: p[ct][r] = P[16w+4g+r][16ct+c15]
  int qrow = 16 * w + c15;
  bf16x8 af = *(const bf16x8*)(qd + ((size_t)(n * GD + qrow)) * 256 + h * HDT + g * 8);

  _Float16 p[32][4];
  #pragma unroll
  for (int ct = 0; ct < 32; ++ct) {
    int krow = 16 * ct + c15;
    bf16x8 bfr = *(const bf16x8*)(kp + ((size_t)(n * GP + krow)) * 256 + h * HDT + g * 8);
    f32x4 acc = __builtin_amdgcn_mfma_f32_16x16x32_bf16(af, bfr, (f32x4){0.f,0.f,0.f,0.f}, 0, 0, 0);
    int mcol = mp_sh[16 * ct + c15];
    #pragma unroll
    for (int r = 0; r < 4; ++r) {
      int row = 16 * w + 4 * g + r;
      p[ct][r] = (_Float16)((mcol && md_sh[row]) ? __expf(acc[r] * 0.17677669529663687f) : 0.f);
    }
  }

  // ---- initial row sums (c == validity)
  {
    float pa0 = 0.f, pa1 = 0.f, pa2 = 0.f, pa3 = 0.f;
    #pragma unroll
    for (int ct = 0; ct < 32; ++ct) {
      pa0 += (float)p[ct][0]; pa1 += (float)p[ct][1];
      pa2 += (float)p[ct][2]; pa3 += (float)p[ct][3];
    }
    #pragma unroll
    for (int m = 1; m <= 8; m <<= 1) {
      pa0 += __shfl_xor(pa0, m, 64); pa1 += __shfl_xor(pa1, m, 64);
      pa2 += __shfl_xor(pa2, m, 64); pa3 += __shfl_xor(pa3, m, 64);
    }
    if (c15 == 0) t_s[16 * w + 4 * g + 0] = pa0;
    if (c15 == 1) t_s[16 * w + 4 * g + 1] = pa1;
    if (c15 == 2) t_s[16 * w + 4 * g + 2] = pa2;
    if (c15 == 3) t_s[16 * w + 4 * g + 3] = pa3;
  }
  __syncthreads();
  if (w == 0) {  // Z = sum of row sums (shuffle tree, no atomics)
    float v = t_s[lane] + t_s[lane + 64];
    #pragma unroll
    for (int m = 1; m <= 32; m <<= 1) v += __shfl_xor(v, m, 64);
    if (lane == 0) z_sh = v;
  }
  __syncthreads();
  float Zinv = 1.0f / z_sh;
  float Sc = kv_sh;

  #pragma unroll 1
  for (int it = 0; it < 4; ++it) {
    // row update
    if (tid < GD) {
      float ti = t_s[tid] * Zinv + 1e-12f * Sc;
      float ri = r_s[tid];
      r_s[tid] = md_sh[tid] ? (ri / (ri * ti + 1e-12f)) : 0.f;
    }
    __syncthreads();
    if (w == 0) {  // Sr
      float v = r_s[lane] + r_s[lane + 64];
      #pragma unroll
      for (int m = 1; m <= 32; m <<= 1) v += __shfl_xor(v, m, 64);
      if (lane == 0) sr_sh = v;
    }
    __syncthreads();
    float Sr = sr_sh;
    // col pass
    float rr0 = r_s[16 * w + 4 * g + 0];
    float rr1 = r_s[16 * w + 4 * g + 1];
    float rr2 = r_s[16 * w + 4 * g + 2];
    float rr3 = r_s[16 * w + 4 * g + 3];
    #pragma unroll
    for (int ct = 0; ct < 32; ++ct) {
      float u = (float)p[ct][0] * rr0 + (float)p[ct][1] * rr1 +
                (float)p[ct][2] * rr2 + (float)p[ct][3] * rr3;
      u += __shfl_xor(u, 16, 64);
      u += __shfl_xor(u, 32, 64);
      if (g == 0) red[w][16 * ct + c15] = u;
    }
    __syncthreads();
    // col update
    {
      float cs = red[0][tid] + red[1][tid] + red[2][tid] + red[3][tid] +
                 red[4][tid] + red[5][tid] + red[6][tid] + red[7][tid];
      float uj = cs * Zinv + 1e-12f * Sr;
      float cj = c_s[tid];
      c_s[tid] = mp_sh[tid] ? (cj / (cj * uj + 1e-12f)) : 0.f;
    }
    __syncthreads();
    if (w == 0) {  // Sc
      float v = c_s[lane] + c_s[lane + 64] + c_s[lane + 128] + c_s[lane + 192] +
                c_s[lane + 256] + c_s[lane + 320] + c_s[lane + 384] + c_s[lane + 448];
      #pragma unroll
      for (int m = 1; m <= 32; m <<= 1) v += __shfl_xor(v, m, 64);
      if (lane == 0) sc_sh = v;
    }
    __syncthreads();
    Sc = sc_sh;
    if (it < 3) {  // row pass for next iteration
      float pa0 = 0.f, pa1 = 0.f, pa2 = 0.f, pa3 = 0.f;
      #pragma unroll
      for (int ct = 0; ct < 32; ++ct) {
        float cv = c_s[16 * ct + c15];
        pa0 += (float)p[ct][0] * cv; pa1 += (float)p[ct][1] * cv;
        pa2 += (float)p[ct][2] * cv; pa3 += (float)p[ct][3] * cv;
      }
      #pragma unroll
      for (int m = 1; m <= 8; m <<= 1) {
        pa0 += __shfl_xor(pa0, m, 64); pa1 += __shfl_xor(pa1, m, 64);
        pa2 += __shfl_xor(pa2, m, 64); pa3 += __shfl_xor(pa3, m, 64);
      }
      if (c15 == 0) t_s[16 * w + 4 * g + 0] = pa0;
      if (c15 == 1) t_s[16 * w + 4 * g + 1] = pa1;
      if (c15 == 2) t_s[16 * w + 4 * g + 2] = pa2;
      if (c15 == 3) t_s[16 * w + 4 * g + 3] = pa3;
      __syncthreads();
    }
  }

  // ---- tiny output: r, c, Zinv
  size_t rb = (size_t)(n * 8 + h) * 1024;
  if (tid < GD) rcz[rb + tid] = r_s[tid];
  if (tid < GP) rcz[rb + 128 + tid] = c_s[tid];
  if (tid == 0) rcz[rb + 640] = Zinv;
}

// ---------------- A writer: recompute P in f32, apply r/c/Zinv --------------
// grid 512; h inner so each lane holds 8 h-values per cell -> 2 float4 stores.
extern "C" __global__ __launch_bounds__(256)
void k_write(const short* __restrict__ qd, const short* __restrict__ kp,
             const float* __restrict__ rcz, float* __restrict__ out) {
  int bid = blockIdx.x;
  int n = ((bid & 7) << 1) | ((bid >> 3) & 1);
  int rest = bid >> 4;
  int rt = rest >> 2;            // row tile (16 rows)
  int cc = rest & 3;             // col chunk (128 cols)
  int w = threadIdx.x >> 6, lane = threadIdx.x & 63;
  int c15 = lane & 15, g = lane >> 4;

  const short* qbase = qd + ((size_t)(n * GD + rt * 16 + c15)) * 256;
  bf16x8 af[8];
  #pragma unroll
  for (int h = 0; h < 8; ++h) af[h] = *(const bf16x8*)(qbase + h * HDT + g * 8);

  size_t rb = (size_t)n * 8 * 1024;
  float rv[8][4], zin[8];
  #pragma unroll
  for (int h = 0; h < 8; ++h) {
    const float* rp = rcz + rb + (size_t)h * 1024;
    #pragma unroll
    for (int r = 0; r < 4; ++r) rv[h][r] = rp[rt * 16 + 4 * g + r];
    zin[h] = rp[640];
  }

  #pragma unroll
  for (int ct = 0; ct < 2; ++ct) {
    int col = cc * 128 + w * 32 + ct * 16 + c15;
    f32x4 acc[8]; float cw[8];
    #pragma unroll
    for (int h = 0; h < 8; ++h) {
      bf16x8 bfr = *(const bf16x8*)(kp + ((size_t)(n * GP + col)) * 256 + h * HDT + g * 8);
      acc[h] = __builtin_amdgcn_mfma_f32_16x16x32_bf16(af[h], bfr, (f32x4){0.f,0.f,0.f,0.f}, 0, 0, 0);
      cw[h] = rcz[rb + (size_t)h * 1024 + 128 + col];
    }
    #pragma unroll
    for (int r = 0; r < 4; ++r) {
      int row = rt * 16 + 4 * g + r;
      float4 lo, hi;
      lo.x = rv[0][r] * (__expf(acc[0][r] * 0.17677669529663687f) * zin[0] + 1e-12f) * cw[0];
      lo.y = rv[1][r] * (__expf(acc[1][r] * 0.17677669529663687f) * zin[1] + 1e-12f) * cw[1];
      lo.z = rv[2][r] * (__expf(acc[2][r] * 0.17677669529663687f) * zin[2] + 1e-12f) * cw[2];
      lo.w = rv[3][r] * (__expf(acc[3][r] * 0.17677669529663687f) * zin[3] + 1e-12f) * cw[3];
      hi.x = rv[4][r] * (__expf(acc[4][r] * 0.17677669529663687f) * zin[4] + 1e-12f) * cw[4];
      hi.y = rv[5][r] * (__expf(acc[5][r] * 0.17677669529663687f) * zin[5] + 1e-12f) * cw[5];
      hi.z = rv[6][r] * (__expf(acc[6][r] * 0.17677669529663687f) * zin[6] + 1e-12f) * cw[6];
      hi.w = rv[7][r] * (__expf(acc[7][r] * 0.17677669529663687f) * zin[7] + 1e-12f) * cw[7];
      float* dst = out + 8192 + (((size_t)(n * GD + row)) * GP + col) * 8;
      *(float4*)dst = lo;
      *(float4*)(dst + 4) = hi;
    }
  }
}

extern "C" void kernel_launch(void* const* d_in, const int* in_sizes, int n_in,
                              void* d_out, int out_size, void* d_ws, size_t ws_size,
                              hipStream_t stream) {
  const float* protein = (const float*)d_in[0];
  const float* drug    = (const float*)d_in[1];
  const int*   mprot   = (const int*)d_in[2];
  const int*   mdrug   = (const int*)d_in[3];
  const float* Wk_p = (const float*)d_in[5];
  const float* Wv_p = (const float*)d_in[6];
  const float* Wq_d = (const float*)d_in[7];
  const float* Wv_d = (const float*)d_in[9];
  float* out = (float*)d_out;

  char* wsb = (char*)d_ws;
  short* pg_bf = (short*)wsb;                 wsb += (size_t)NB * GP * 256 * 2;  // 4 MB
  short* dg_bf = (short*)wsb;                 wsb += (size_t)NB * GD * 256 * 2;  // 1 MB
  short* kp_bf = (short*)wsb;                 wsb += (size_t)NB * GP * 256 * 2;  // 4 MB
  short* qd_bf = (short*)wsb;                 wsb += (size_t)NB * GD * 256 * 2;  // 1 MB
  short* Wk_bf = (short*)wsb;                 wsb += 65536 * 2;
  short* Wq_bf = (short*)wsb;                 wsb += 65536 * 2;
  float* part  = (float*)wsb;                 wsb += (size_t)320 * 256 * 4;      // 320 KB
  float* rcz   = (float*)wsb;                 wsb += (size_t)128 * 1024 * 4;     // 512 KB
  int*   cntp  = (int*)wsb;                   wsb += 320 * 4;
  int*   mp_g  = (int*)wsb;                   wsb += 8192 * 4;
  int*   md_g  = (int*)wsb;                   wsb += 2048 * 4;

  k_group<<<576, 256, 0, stream>>>(protein, drug, mprot, mdrug, Wk_p, Wq_d,
                                   pg_bf, dg_bf, mp_g, md_g, Wk_bf, Wq_bf,
                                   part, cntp);
  k_proj_embed<<<288, 256, 0, stream>>>(pg_bf, dg_bf, Wk_bf, Wq_bf, kp_bf, qd_bf,
                                        part, cntp, Wv_p, Wv_d, out);
  k_scalars<<<128, 512, 0, stream>>>(qd_bf, kp_bf, md_g, mp_g, rcz);
  k_write<<<512, 256, 0, stream>>>(qd_bf, kp_bf, rcz, out);
}

// Round 5
// 186.506 us; speedup vs baseline: 1.5343x; 1.0013x over previous
//
#include <hip/hip_runtime.h>
#include <hip/hip_bf16.h>

// Sizes (fixed by the problem)
#define NB   16      // batch
#define DT   256     // model dim
#define HT   8       // heads
#define HDT  32      // head dim
#define GP   512     // protein groups (2048/4)
#define GD   128     // drug groups (512/4)
#define SCL  0.17677669529663687f

using bf16x8 = __attribute__((ext_vector_type(8))) short;
using f32x4  = __attribute__((ext_vector_type(4))) float;

__device__ __forceinline__ short f2bf(float f) {
  __hip_bfloat16 h = __float2bfloat16(f);
  short s; __builtin_memcpy(&s, &h, 2);
  return s;
}

__device__ __forceinline__ bf16x8 cvt8(float4 a, float4 b) {
  bf16x8 r;
  r[0] = f2bf(a.x); r[1] = f2bf(a.y); r[2] = f2bf(a.z); r[3] = f2bf(a.w);
  r[4] = f2bf(b.x); r[5] = f2bf(b.y); r[6] = f2bf(b.z); r[7] = f2bf(b.w);
  return r;
}

// ============ k1: fused grouping + masks + part sums + projection ===========
// blocks 0..127: protein (64 grouped rows each) -> kp_bf; 128..159: drug -> qd_bf.
// Grouping (mean over 4 src rows) fused into A-fragment load; W cvt in-register;
// masked per-block column sums of group means -> part[b][256]; counts -> cntp[b].
extern "C" __global__ __launch_bounds__(256)
void k_fused_proj(const float* __restrict__ protein, const float* __restrict__ drug,
                  const int* __restrict__ mprot, const int* __restrict__ mdrug,
                  const float* __restrict__ Wk, const float* __restrict__ Wq,
                  short* __restrict__ kp_bf, short* __restrict__ qd_bf,
                  int* __restrict__ mp_g, int* __restrict__ md_g,
                  float* __restrict__ part, int* __restrict__ cntp) {
  int b = blockIdx.x, t = threadIdx.x;
  int w = t >> 6, lane = t & 63, c15 = lane & 15, g = lane >> 4;
  const float *src, *W; const int* msk; short* o; int* mg;
  int bb;
  if (b < 128) { bb = b;      src = protein; msk = mprot; W = Wk; o = kp_bf; mg = mp_g; }
  else         { bb = b - 128; src = drug;   msk = mdrug; W = Wq; o = qd_bf; mg = md_g; }
  int flatrow0 = bb * 64;   // grouped-row base (flat over n,G)

  __shared__ int gm_s[64];
  __shared__ float part_s[256];
  part_s[t] = 0.f;
  if (t < 64) {
    const int* m = msk + (size_t)(flatrow0 + t) * 4;
    int v = (m[0] | m[1] | m[2] | m[3]) ? 1 : 0;
    gm_s[t] = v;
    mg[flatrow0 + t] = v;
  }
  __syncthreads();
  if (t == 0) {
    int c = 0;
    #pragma unroll
    for (int i = 0; i < 64; ++i) c += gm_s[i];
    cntp[b] = c;
  }

  int grow = flatrow0 + w * 16 + c15;
  const float* ap = src + (size_t)grow * 1024;   // 4 src rows of 256
  int msel = gm_s[w * 16 + c15];

  f32x4 acc[16];
  #pragma unroll
  for (int i = 0; i < 16; ++i) acc[i] = (f32x4){0.f, 0.f, 0.f, 0.f};

  #pragma unroll
  for (int ks = 0; ks < 8; ++ks) {
    int k0 = ks * 32 + g * 8;
    float4 s0  = *(const float4*)(ap + k0);
    float4 s0b = *(const float4*)(ap + k0 + 4);
    float4 s1  = *(const float4*)(ap + 256 + k0);
    float4 s1b = *(const float4*)(ap + 256 + k0 + 4);
    float4 s2  = *(const float4*)(ap + 512 + k0);
    float4 s2b = *(const float4*)(ap + 512 + k0 + 4);
    float4 s3  = *(const float4*)(ap + 768 + k0);
    float4 s3b = *(const float4*)(ap + 768 + k0 + 4);
    float4 av, bv;
    av.x = 0.25f * (s0.x + s1.x + s2.x + s3.x);
    av.y = 0.25f * (s0.y + s1.y + s2.y + s3.y);
    av.z = 0.25f * (s0.z + s1.z + s2.z + s3.z);
    av.w = 0.25f * (s0.w + s1.w + s2.w + s3.w);
    bv.x = 0.25f * (s0b.x + s1b.x + s2b.x + s3b.x);
    bv.y = 0.25f * (s0b.y + s1b.y + s2b.y + s3b.y);
    bv.z = 0.25f * (s0b.z + s1b.z + s2b.z + s3b.z);
    bv.w = 0.25f * (s0b.w + s1b.w + s2b.w + s3b.w);
    bf16x8 af = cvt8(av, bv);

    // masked part contribution: sum over this tile's 16 rows (c15 lanes)
    float vs[8];
    vs[0] = msel ? av.x : 0.f; vs[1] = msel ? av.y : 0.f;
    vs[2] = msel ? av.z : 0.f; vs[3] = msel ? av.w : 0.f;
    vs[4] = msel ? bv.x : 0.f; vs[5] = msel ? bv.y : 0.f;
    vs[6] = msel ? bv.z : 0.f; vs[7] = msel ? bv.w : 0.f;
    #pragma unroll
    for (int j = 0; j < 8; ++j) {
      #pragma unroll
      for (int m = 1; m <= 8; m <<= 1) vs[j] += __shfl_xor(vs[j], m, 64);
    }
    if (c15 == 0) {
      #pragma unroll
      for (int j = 0; j < 8; ++j) atomicAdd(&part_s[k0 + j], vs[j]);
    }

    #pragma unroll
    for (int ct = 0; ct < 16; ++ct) {
      const float* wp = W + (size_t)(ct * 16 + c15) * 256 + k0;
      bf16x8 bfr = cvt8(*(const float4*)wp, *(const float4*)(wp + 4));
      acc[ct] = __builtin_amdgcn_mfma_f32_16x16x32_bf16(af, bfr, acc[ct], 0, 0, 0);
    }
  }
  #pragma unroll
  for (int ct = 0; ct < 16; ++ct) {
    #pragma unroll
    for (int r = 0; r < 4; ++r) {
      o[(size_t)(flatrow0 + w * 16 + 4 * g + r) * 256 + ct * 16 + c15] = f2bf(acc[ct][r]);
    }
  }
  __syncthreads();
  part[(size_t)b * 256 + t] = part_s[t];
}

// ============ k2: dp sinkhorn scalars, 1024 threads, P in named registers ====
// One block per (n,h); 16 waves: wr=wid>>1 row-group (16 rows), ch=wid&1 col-half.
// P[16 ct][4 r] held in 16 named f32x4 regs (64 VGPR) -> no scratch demotion.
// Outputs r[128], c[512], Zinv per (n,h) into rcz (stride 1024 floats).
#define FOR16(X) X(0) X(1) X(2) X(3) X(4) X(5) X(6) X(7) X(8) X(9) X(10) X(11) X(12) X(13) X(14) X(15)

extern "C" __global__ __launch_bounds__(1024)
void k_scalars(const short* __restrict__ qd, const short* __restrict__ kp,
               const int* __restrict__ md_g, const int* __restrict__ mp_g,
               float* __restrict__ rcz) {
  int bid = blockIdx.x;
  int n = ((bid & 7) << 1) | ((bid >> 3) & 1);   // XCD swizzle: h-blocks of n share L2
  int h = bid >> 4;
  int tid = threadIdx.x;
  int wid = tid >> 6, lane = tid & 63;
  int wr = wid >> 1, ch = wid & 1;
  int c15 = lane & 15, g = lane >> 4;

  __shared__ float c_s[GP];
  __shared__ float r_s[GD];
  __shared__ float t_s[GD];
  __shared__ float t2[2][GD];
  __shared__ float red[8][GP];
  __shared__ float z_sh, sr_sh, sc_sh, kv_sh;
  __shared__ int mp_sh[GP];
  __shared__ int md_sh[GD];

  if (tid < GP) { int m = mp_g[n * GP + tid]; mp_sh[tid] = m; c_s[tid] = m ? 1.f : 0.f; }
  if (tid < GD) { int m = md_g[n * GD + tid]; md_sh[tid] = m; r_s[tid] = m ? 1.f : 0.f; }
  __syncthreads();

  if (wid == 0) {  // Kv = sum mp
    float v = (float)(mp_sh[lane] + mp_sh[lane + 64] + mp_sh[lane + 128] + mp_sh[lane + 192] +
                      mp_sh[lane + 256] + mp_sh[lane + 320] + mp_sh[lane + 384] + mp_sh[lane + 448]);
    #pragma unroll
    for (int m = 1; m <= 32; m <<= 1) v += __shfl_xor(v, m, 64);
    if (lane == 0) kv_sh = v;
  }

  // ---- logits via MFMA, P = exp(masked logit) in named registers
  int qrow = 16 * wr + c15;
  bf16x8 af = *(const bf16x8*)(qd + ((size_t)(n * GD + qrow)) * 256 + h * HDT + g * 8);
  int row0 = 16 * wr + 4 * g;
  int mr0 = md_sh[row0], mr1 = md_sh[row0 + 1], mr2 = md_sh[row0 + 2], mr3 = md_sh[row0 + 3];
  const short* kbase = kp + ((size_t)n * GP) * 256 + h * HDT + g * 8;
  int colbase = ch * 256 + c15;

#define DECLP(i) f32x4 P##i;
  FOR16(DECLP)
#define MKP(i) { int col = colbase + 16 * (i); \
    bf16x8 bfr = *(const bf16x8*)(kbase + (size_t)col * 256); \
    f32x4 a = __builtin_amdgcn_mfma_f32_16x16x32_bf16(af, bfr, (f32x4){0.f,0.f,0.f,0.f}, 0, 0, 0); \
    int mc = mp_sh[col]; \
    P##i[0] = (mc && mr0) ? __expf(a[0] * SCL) : 0.f; \
    P##i[1] = (mc && mr1) ? __expf(a[1] * SCL) : 0.f; \
    P##i[2] = (mc && mr2) ? __expf(a[2] * SCL) : 0.f; \
    P##i[3] = (mc && mr3) ? __expf(a[3] * SCL) : 0.f; }
  FOR16(MKP)

  // ---- initial row sums (c == validity, already folded into P zeros)
  {
    float pa0 = 0.f, pa1 = 0.f, pa2 = 0.f, pa3 = 0.f;
#define RS0(i) pa0 += P##i[0]; pa1 += P##i[1]; pa2 += P##i[2]; pa3 += P##i[3];
    FOR16(RS0)
    #pragma unroll
    for (int m = 1; m <= 8; m <<= 1) {
      pa0 += __shfl_xor(pa0, m, 64); pa1 += __shfl_xor(pa1, m, 64);
      pa2 += __shfl_xor(pa2, m, 64); pa3 += __shfl_xor(pa3, m, 64);
    }
    if (c15 == 0) t2[ch][row0 + 0] = pa0;
    if (c15 == 1) t2[ch][row0 + 1] = pa1;
    if (c15 == 2) t2[ch][row0 + 2] = pa2;
    if (c15 == 3) t2[ch][row0 + 3] = pa3;
  }
  __syncthreads();
  if (tid < GD) t_s[tid] = t2[0][tid] + t2[1][tid];
  __syncthreads();
  if (wid == 0) {  // Z
    float v = t_s[lane] + t_s[lane + 64];
    #pragma unroll
    for (int m = 1; m <= 32; m <<= 1) v += __shfl_xor(v, m, 64);
    if (lane == 0) z_sh = v;
  }
  __syncthreads();
  float Zinv = 1.0f / z_sh;
  float Sc = kv_sh;

  #pragma unroll 1
  for (int it = 0; it < 4; ++it) {
    // row update
    if (tid < GD) {
      float ti = t_s[tid] * Zinv + 1e-12f * Sc;
      float ri = r_s[tid];
      r_s[tid] = md_sh[tid] ? (ri / (ri * ti + 1e-12f)) : 0.f;
    }
    __syncthreads();
    if (wid == 0) {  // Sr
      float v = r_s[lane] + r_s[lane + 64];
      #pragma unroll
      for (int m = 1; m <= 32; m <<= 1) v += __shfl_xor(v, m, 64);
      if (lane == 0) sr_sh = v;
    }
    __syncthreads();
    float Sr = sr_sh;
    // col pass: partial col sums over this wave's 16 rows
    {
      float rr0 = r_s[row0], rr1 = r_s[row0 + 1], rr2 = r_s[row0 + 2], rr3 = r_s[row0 + 3];
#define CP(i) { float u = P##i[0] * rr0 + P##i[1] * rr1 + P##i[2] * rr2 + P##i[3] * rr3; \
      u += __shfl_xor(u, 16, 64); u += __shfl_xor(u, 32, 64); \
      if (g == 0) red[wr][colbase + 16 * (i)] = u; }
      FOR16(CP)
    }
    __syncthreads();
    // col update
    if (tid < GP) {
      float cs = red[0][tid] + red[1][tid] + red[2][tid] + red[3][tid] +
                 red[4][tid] + red[5][tid] + red[6][tid] + red[7][tid];
      float uj = cs * Zinv + 1e-12f * Sr;
      float cj = c_s[tid];
      c_s[tid] = mp_sh[tid] ? (cj / (cj * uj + 1e-12f)) : 0.f;
    }
    __syncthreads();
    if (wid == 0) {  // Sc
      float v = c_s[lane] + c_s[lane + 64] + c_s[lane + 128] + c_s[lane + 192] +
                c_s[lane + 256] + c_s[lane + 320] + c_s[lane + 384] + c_s[lane + 448];
      #pragma unroll
      for (int m = 1; m <= 32; m <<= 1) v += __shfl_xor(v, m, 64);
      if (lane == 0) sc_sh = v;
    }
    __syncthreads();
    Sc = sc_sh;
    if (it < 3) {  // row pass for next iteration
      float qa0 = 0.f, qa1 = 0.f, qa2 = 0.f, qa3 = 0.f;
#define RP(i) { float cv = c_s[colbase + 16 * (i)]; \
      qa0 += P##i[0] * cv; qa1 += P##i[1] * cv; qa2 += P##i[2] * cv; qa3 += P##i[3] * cv; }
      FOR16(RP)
      #pragma unroll
      for (int m = 1; m <= 8; m <<= 1) {
        qa0 += __shfl_xor(qa0, m, 64); qa1 += __shfl_xor(qa1, m, 64);
        qa2 += __shfl_xor(qa2, m, 64); qa3 += __shfl_xor(qa3, m, 64);
      }
      if (c15 == 0) t2[ch][row0 + 0] = qa0;
      if (c15 == 1) t2[ch][row0 + 1] = qa1;
      if (c15 == 2) t2[ch][row0 + 2] = qa2;
      if (c15 == 3) t2[ch][row0 + 3] = qa3;
      __syncthreads();
      if (tid < GD) t_s[tid] = t2[0][tid] + t2[1][tid];
      // no barrier needed: row update next iter reads t_s[tid] in the same threads
    }
  }

  // ---- tiny output: r, c, Zinv
  size_t rb = (size_t)(n * 8 + h) * 1024;
  if (tid < GD) rcz[rb + tid] = r_s[tid];
  if (tid < GP) rcz[rb + 128 + tid] = c_s[tid];
  if (tid == 0) rcz[rb + 640] = Zinv;
}

// ============ k3: A writer (blocks 0..511) + query_embed (512..639) ==========
extern "C" __global__ __launch_bounds__(256)
void k_write_embed(const short* __restrict__ qd, const short* __restrict__ kp,
                   const float* __restrict__ rcz,
                   const float* __restrict__ part, const int* __restrict__ cntp,
                   const float* __restrict__ Wvp, const float* __restrict__ Wvd,
                   float* __restrict__ out) {
  int bid = blockIdx.x;
  int t = threadIdx.x;
  if (bid >= 512) {  // ---- embed: 0.5*(sp@Wvp^T + sd@Wvd^T)/cnt ----
    int bb = bid - 512;
    int n = bb >> 3;
    int dchunk = (bb & 7) * 32;
    __shared__ float sps[256], sds[256];
    float a1 = 0.f;
    #pragma unroll
    for (int i = 0; i < 8; ++i) a1 += part[(size_t)(n * 8 + i) * 256 + t];
    sps[t] = a1;
    float a2 = 0.f;
    #pragma unroll
    for (int i = 0; i < 2; ++i) a2 += part[(size_t)(128 + n * 2 + i) * 256 + t];
    sds[t] = a2;
    __syncthreads();
    int cp = 0, cd = 0;
    #pragma unroll
    for (int i = 0; i < 8; ++i) cp += cntp[n * 8 + i];
    #pragma unroll
    for (int i = 0; i < 2; ++i) cd += cntp[128 + n * 2 + i];
    int dloc = t >> 3, ks = (t & 7) * 32;
    int d = dchunk + dloc;
    const float* wp = Wvp + (size_t)d * 256 + ks;
    const float* wd = Wvd + (size_t)d * 256 + ks;
    float acc = 0.f;
    #pragma unroll
    for (int k = 0; k < 32; k += 4) {
      float4 a = *(const float4*)(wp + k);
      float4 c = *(const float4*)(wd + k);
      acc += sps[ks + k] * a.x + sps[ks + k + 1] * a.y + sps[ks + k + 2] * a.z + sps[ks + k + 3] * a.w
           + sds[ks + k] * c.x + sds[ks + k + 1] * c.y + sds[ks + k + 2] * c.z + sds[ks + k + 3] * c.w;
    }
    #pragma unroll
    for (int m = 1; m <= 4; m <<= 1) acc += __shfl_xor(acc, m, 64);
    if ((t & 7) == 0) {
      acc *= 0.5f;
      out[n * 512 + d]       = acc / (float)cp;
      out[n * 512 + 256 + d] = acc / (float)cd;
    }
    return;
  }
  // ---- A writer: recompute P in f32, apply r/c/Zinv; h-contiguous stores ----
  int n = ((bid & 7) << 1) | ((bid >> 3) & 1);
  int rest = bid >> 4;
  int rt = rest >> 2;            // row tile (16 rows)
  int cc = rest & 3;             // col chunk (128 cols)
  int w = t >> 6, lane = t & 63;
  int c15 = lane & 15, g = lane >> 4;

  const short* qbase = qd + ((size_t)(n * GD + rt * 16 + c15)) * 256;
  bf16x8 af[8];
  #pragma unroll
  for (int h = 0; h < 8; ++h) af[h] = *(const bf16x8*)(qbase + h * HDT + g * 8);

  size_t rb = (size_t)n * 8 * 1024;
  float rv[8][4], zin[8];
  #pragma unroll
  for (int h = 0; h < 8; ++h) {
    const float* rp = rcz + rb + (size_t)h * 1024;
    #pragma unroll
    for (int r = 0; r < 4; ++r) rv[h][r] = rp[rt * 16 + 4 * g + r];
    zin[h] = rp[640];
  }

  #pragma unroll
  for (int ct = 0; ct < 2; ++ct) {
    int col = cc * 128 + w * 32 + ct * 16 + c15;
    f32x4 acc[8]; float cw[8];
    #pragma unroll
    for (int h = 0; h < 8; ++h) {
      bf16x8 bfr = *(const bf16x8*)(kp + ((size_t)(n * GP + col)) * 256 + h * HDT + g * 8);
      acc[h] = __builtin_amdgcn_mfma_f32_16x16x32_bf16(af[h], bfr, (f32x4){0.f,0.f,0.f,0.f}, 0, 0, 0);
      cw[h] = rcz[rb + (size_t)h * 1024 + 128 + col];
    }
    #pragma unroll
    for (int r = 0; r < 4; ++r) {
      int row = rt * 16 + 4 * g + r;
      float4 lo, hi;
      lo.x = rv[0][r] * (__expf(acc[0][r] * SCL) * zin[0] + 1e-12f) * cw[0];
      lo.y = rv[1][r] * (__expf(acc[1][r] * SCL) * zin[1] + 1e-12f) * cw[1];
      lo.z = rv[2][r] * (__expf(acc[2][r] * SCL) * zin[2] + 1e-12f) * cw[2];
      lo.w = rv[3][r] * (__expf(acc[3][r] * SCL) * zin[3] + 1e-12f) * cw[3];
      hi.x = rv[4][r] * (__expf(acc[4][r] * SCL) * zin[4] + 1e-12f) * cw[4];
      hi.y = rv[5][r] * (__expf(acc[5][r] * SCL) * zin[5] + 1e-12f) * cw[5];
      hi.z = rv[6][r] * (__expf(acc[6][r] * SCL) * zin[6] + 1e-12f) * cw[6];
      hi.w = rv[7][r] * (__expf(acc[7][r] * SCL) * zin[7] + 1e-12f) * cw[7];
      float* dst = out + 8192 + (((size_t)(n * GD + row)) * GP + col) * 8;
      *(float4*)dst = lo;
      *(float4*)(dst + 4) = hi;
    }
  }
}

extern "C" void kernel_launch(void* const* d_in, const int* in_sizes, int n_in,
                              void* d_out, int out_size, void* d_ws, size_t ws_size,
                              hipStream_t stream) {
  const float* protein = (const float*)d_in[0];
  const float* drug    = (const float*)d_in[1];
  const int*   mprot   = (const int*)d_in[2];
  const int*   mdrug   = (const int*)d_in[3];
  const float* Wk_p = (const float*)d_in[5];
  const float* Wv_p = (const float*)d_in[6];
  const float* Wq_d = (const float*)d_in[7];
  const float* Wv_d = (const float*)d_in[9];
  float* out = (float*)d_out;

  char* wsb = (char*)d_ws;
  short* kp_bf = (short*)wsb;                 wsb += (size_t)NB * GP * 256 * 2;  // 4 MB
  short* qd_bf = (short*)wsb;                 wsb += (size_t)NB * GD * 256 * 2;  // 1 MB
  float* part  = (float*)wsb;                 wsb += (size_t)160 * 256 * 4;      // 160 KB
  float* rcz   = (float*)wsb;                 wsb += (size_t)128 * 1024 * 4;     // 512 KB
  int*   cntp  = (int*)wsb;                   wsb += 160 * 4;
  int*   mp_g  = (int*)wsb;                   wsb += 8192 * 4;
  int*   md_g  = (int*)wsb;                   wsb += 2048 * 4;

  k_fused_proj<<<160, 256, 0, stream>>>(protein, drug, mprot, mdrug, Wk_p, Wq_d,
                                        kp_bf, qd_bf, mp_g, md_g, part, cntp);
  k_scalars<<<128, 1024, 0, stream>>>(qd_bf, kp_bf, md_g, mp_g, rcz);
  k_write_embed<<<640, 256, 0, stream>>>(qd_bf, kp_bf, rcz, part, cntp,
                                         Wv_p, Wv_d, out);
}

// Round 6
// 163.150 us; speedup vs baseline: 1.7539x; 1.1432x over previous
//
#include <hip/hip_runtime.h>
#include <hip/hip_bf16.h>

// Sizes (fixed by the problem)
#define NB   16      // batch
#define DT   256     // model dim
#define HT   8       // heads
#define HDT  32      // head dim
#define GP   512     // protein groups (2048/4)
#define GD   128     // drug groups (512/4)
#define SCL  0.17677669529663687f

using bf16x8 = __attribute__((ext_vector_type(8))) short;
using bf16x4 = __attribute__((ext_vector_type(4))) short;
using f32x4  = __attribute__((ext_vector_type(4))) float;

__device__ __forceinline__ short f2bf(float f) {
  __hip_bfloat16 h = __float2bfloat16(f);
  short s; __builtin_memcpy(&s, &h, 2);
  return s;
}

__device__ __forceinline__ bf16x8 cvt8(float4 a, float4 b) {
  bf16x8 r;
  r[0] = f2bf(a.x); r[1] = f2bf(a.y); r[2] = f2bf(a.z); r[3] = f2bf(a.w);
  r[4] = f2bf(b.x); r[5] = f2bf(b.y); r[6] = f2bf(b.z); r[7] = f2bf(b.w);
  return r;
}

// ============ k1: grouping (f32 -> grouped bf16) + masks + part sums + W cvt
// blocks 0..511: protein, 16 groups each; 512..639: drug, 16 groups each;
// 640..703: convert Wk/Wq to bf16 (2048 elems each).
// Thread: col4 = t&63 (4 cols), gsub = t>>6; 4 iterations of 4 groups.
extern "C" __global__ __launch_bounds__(256)
void k_group(const float* __restrict__ protein, const float* __restrict__ drug,
             const int* __restrict__ mprot, const int* __restrict__ mdrug,
             const float* __restrict__ Wk, const float* __restrict__ Wq,
             short* __restrict__ pg_bf, short* __restrict__ dg_bf,
             int* __restrict__ mp_g, int* __restrict__ md_g,
             short* __restrict__ Wk_bf, short* __restrict__ Wq_bf,
             float* __restrict__ part, int* __restrict__ cntp) {
  int b = blockIdx.x, t = threadIdx.x;
  if (b >= 640) {  // ---- W conversion ----
    int idx = (b - 640) * 2048 + t * 8;
    const float* s; short* d;
    if (idx < 65536) { s = Wk + idx; d = Wk_bf + idx; }
    else             { s = Wq + (idx - 65536); d = Wq_bf + (idx - 65536); }
    *(bf16x8*)d = cvt8(*(const float4*)s, *(const float4*)(s + 4));
    return;
  }
  const float* src; const int* msk; short* dst; int* mg; int gbase;
  if (b < 512) { src = protein; msk = mprot; dst = pg_bf; mg = mp_g; gbase = b * 16; }
  else         { src = drug;    msk = mdrug; dst = dg_bf; mg = md_g; gbase = (b - 512) * 16; }

  __shared__ int gm_s[16];
  __shared__ float part_s[4][256];
  if (t < 16) {
    const int* m = msk + (size_t)(gbase + t) * 4;
    int v = (m[0] | m[1] | m[2] | m[3]) ? 1 : 0;
    gm_s[t] = v;
    mg[gbase + t] = v;
  }
  __syncthreads();
  if (t == 0) {
    int c = 0;
    #pragma unroll
    for (int i = 0; i < 16; ++i) c += gm_s[i];
    cntp[b] = c;
  }

  int col4 = t & 63, gsub = t >> 6;
  float a0 = 0.f, a1 = 0.f, a2 = 0.f, a3 = 0.f;
  #pragma unroll
  for (int it = 0; it < 4; ++it) {
    int grp = gbase + gsub + it * 4;
    const float* rp = src + (size_t)grp * 1024 + col4 * 4;
    float4 r0 = *(const float4*)rp;
    float4 r1 = *(const float4*)(rp + 256);
    float4 r2 = *(const float4*)(rp + 512);
    float4 r3 = *(const float4*)(rp + 768);
    float m0 = 0.25f * (r0.x + r1.x + r2.x + r3.x);
    float m1 = 0.25f * (r0.y + r1.y + r2.y + r3.y);
    float m2 = 0.25f * (r0.z + r1.z + r2.z + r3.z);
    float m3 = 0.25f * (r0.w + r1.w + r2.w + r3.w);
    bf16x4 v; v[0] = f2bf(m0); v[1] = f2bf(m1); v[2] = f2bf(m2); v[3] = f2bf(m3);
    *(bf16x4*)(dst + (size_t)grp * 256 + col4 * 4) = v;
    if (gm_s[gsub + it * 4]) { a0 += m0; a1 += m1; a2 += m2; a3 += m3; }
  }
  part_s[gsub][col4 * 4 + 0] = a0;
  part_s[gsub][col4 * 4 + 1] = a1;
  part_s[gsub][col4 * 4 + 2] = a2;
  part_s[gsub][col4 * 4 + 3] = a3;
  __syncthreads();
  part[(size_t)b * 256 + t] = part_s[0][t] + part_s[1][t] + part_s[2][t] + part_s[3][t];
}

// ============ k2: bf16 projection GEMM, wave = 16 rows x 128 cols ============
// blocks 0..255: kp = pg@Wk^T (32 rows/block, 2 col-halves); 256..319: qd.
extern "C" __global__ __launch_bounds__(256)
void k_projbf(const short* __restrict__ pg_bf, const short* __restrict__ dg_bf,
              const short* __restrict__ Wk_bf, const short* __restrict__ Wq_bf,
              short* __restrict__ kp_bf, short* __restrict__ qd_bf) {
  int b = blockIdx.x, t = threadIdx.x;
  int w = t >> 6, lane = t & 63, c15 = lane & 15, g = lane >> 4;
  const short *A, *W; short* o; int rowbase;
  if (b < 256) { A = pg_bf; W = Wk_bf; o = kp_bf; rowbase = b * 32; }
  else         { A = dg_bf; W = Wq_bf; o = qd_bf; rowbase = (b - 256) * 32; }
  int rt = rowbase + (w & 1) * 16;
  int ch = (w >> 1) * 128;

  const short* ap = A + (size_t)(rt + c15) * 256;
  f32x4 acc[8];
  #pragma unroll
  for (int i = 0; i < 8; ++i) acc[i] = (f32x4){0.f, 0.f, 0.f, 0.f};

  #pragma unroll
  for (int ks = 0; ks < 8; ++ks) {
    bf16x8 af = *(const bf16x8*)(ap + ks * 32 + g * 8);
    #pragma unroll
    for (int ct = 0; ct < 8; ++ct) {
      bf16x8 bfr = *(const bf16x8*)(W + (size_t)(ch + ct * 16 + c15) * 256 + ks * 32 + g * 8);
      acc[ct] = __builtin_amdgcn_mfma_f32_16x16x32_bf16(af, bfr, acc[ct], 0, 0, 0);
    }
  }
  #pragma unroll
  for (int ct = 0; ct < 8; ++ct) {
    #pragma unroll
    for (int r = 0; r < 4; ++r) {
      o[(size_t)(rt + 4 * g + r) * 256 + ch + ct * 16 + c15] = f2bf(acc[ct][r]);
    }
  }
}

// ============ k3: dp sinkhorn scalars, 1024 threads, P in named registers ====
// One block per (n,h); 16 waves: wr=wid>>1 row-group (16 rows), ch=wid&1 col-half.
// Outputs r[128], c[512], Zinv per (n,h) into rcz (stride 1024 floats).
#define FOR16(X) X(0) X(1) X(2) X(3) X(4) X(5) X(6) X(7) X(8) X(9) X(10) X(11) X(12) X(13) X(14) X(15)

extern "C" __global__ __launch_bounds__(1024)
void k_scalars(const short* __restrict__ qd, const short* __restrict__ kp,
               const int* __restrict__ md_g, const int* __restrict__ mp_g,
               float* __restrict__ rcz) {
  int bid = blockIdx.x;
  int n = ((bid & 7) << 1) | ((bid >> 3) & 1);   // XCD swizzle: h-blocks of n share L2
  int h = bid >> 4;
  int tid = threadIdx.x;
  int wid = tid >> 6, lane = tid & 63;
  int wr = wid >> 1, ch = wid & 1;
  int c15 = lane & 15, g = lane >> 4;

  __shared__ float c_s[GP];
  __shared__ float r_s[GD];
  __shared__ float t_s[GD];
  __shared__ float t2[2][GD];
  __shared__ float red[8][GP];
  __shared__ float z_sh, sr_sh, sc_sh, kv_sh;
  __shared__ int mp_sh[GP];
  __shared__ int md_sh[GD];

  if (tid < GP) { int m = mp_g[n * GP + tid]; mp_sh[tid] = m; c_s[tid] = m ? 1.f : 0.f; }
  if (tid < GD) { int m = md_g[n * GD + tid]; md_sh[tid] = m; r_s[tid] = m ? 1.f : 0.f; }
  __syncthreads();

  if (wid == 0) {  // Kv = sum mp
    float v = (float)(mp_sh[lane] + mp_sh[lane + 64] + mp_sh[lane + 128] + mp_sh[lane + 192] +
                      mp_sh[lane + 256] + mp_sh[lane + 320] + mp_sh[lane + 384] + mp_sh[lane + 448]);
    #pragma unroll
    for (int m = 1; m <= 32; m <<= 1) v += __shfl_xor(v, m, 64);
    if (lane == 0) kv_sh = v;
  }

  // ---- logits via MFMA, P = exp(masked logit) in named registers
  int qrow = 16 * wr + c15;
  bf16x8 af = *(const bf16x8*)(qd + ((size_t)(n * GD + qrow)) * 256 + h * HDT + g * 8);
  int row0 = 16 * wr + 4 * g;
  int mr0 = md_sh[row0], mr1 = md_sh[row0 + 1], mr2 = md_sh[row0 + 2], mr3 = md_sh[row0 + 3];
  const short* kbase = kp + ((size_t)n * GP) * 256 + h * HDT + g * 8;
  int colbase = ch * 256 + c15;

#define DECLP(i) f32x4 P##i;
  FOR16(DECLP)
#define MKP(i) { int col = colbase + 16 * (i); \
    bf16x8 bfr = *(const bf16x8*)(kbase + (size_t)col * 256); \
    f32x4 a = __builtin_amdgcn_mfma_f32_16x16x32_bf16(af, bfr, (f32x4){0.f,0.f,0.f,0.f}, 0, 0, 0); \
    int mc = mp_sh[col]; \
    P##i[0] = (mc && mr0) ? __expf(a[0] * SCL) : 0.f; \
    P##i[1] = (mc && mr1) ? __expf(a[1] * SCL) : 0.f; \
    P##i[2] = (mc && mr2) ? __expf(a[2] * SCL) : 0.f; \
    P##i[3] = (mc && mr3) ? __expf(a[3] * SCL) : 0.f; }
  FOR16(MKP)

  // ---- initial row sums
  {
    float pa0 = 0.f, pa1 = 0.f, pa2 = 0.f, pa3 = 0.f;
#define RS0(i) pa0 += P##i[0]; pa1 += P##i[1]; pa2 += P##i[2]; pa3 += P##i[3];
    FOR16(RS0)
    #pragma unroll
    for (int m = 1; m <= 8; m <<= 1) {
      pa0 += __shfl_xor(pa0, m, 64); pa1 += __shfl_xor(pa1, m, 64);
      pa2 += __shfl_xor(pa2, m, 64); pa3 += __shfl_xor(pa3, m, 64);
    }
    if (c15 == 0) t2[ch][row0 + 0] = pa0;
    if (c15 == 1) t2[ch][row0 + 1] = pa1;
    if (c15 == 2) t2[ch][row0 + 2] = pa2;
    if (c15 == 3) t2[ch][row0 + 3] = pa3;
  }
  __syncthreads();
  if (tid < GD) t_s[tid] = t2[0][tid] + t2[1][tid];
  __syncthreads();
  if (wid == 0) {  // Z
    float v = t_s[lane] + t_s[lane + 64];
    #pragma unroll
    for (int m = 1; m <= 32; m <<= 1) v += __shfl_xor(v, m, 64);
    if (lane == 0) z_sh = v;
  }
  __syncthreads();
  float Zinv = 1.0f / z_sh;
  float Sc = kv_sh;

  #pragma unroll 1
  for (int it = 0; it < 4; ++it) {
    // row update
    if (tid < GD) {
      float ti = t_s[tid] * Zinv + 1e-12f * Sc;
      float ri = r_s[tid];
      r_s[tid] = md_sh[tid] ? (ri / (ri * ti + 1e-12f)) : 0.f;
    }
    __syncthreads();
    if (wid == 0) {  // Sr
      float v = r_s[lane] + r_s[lane + 64];
      #pragma unroll
      for (int m = 1; m <= 32; m <<= 1) v += __shfl_xor(v, m, 64);
      if (lane == 0) sr_sh = v;
    }
    __syncthreads();
    float Sr = sr_sh;
    // col pass: partial col sums over this wave's 16 rows
    {
      float rr0 = r_s[row0], rr1 = r_s[row0 + 1], rr2 = r_s[row0 + 2], rr3 = r_s[row0 + 3];
#define CP(i) { float u = P##i[0] * rr0 + P##i[1] * rr1 + P##i[2] * rr2 + P##i[3] * rr3; \
      u += __shfl_xor(u, 16, 64); u += __shfl_xor(u, 32, 64); \
      if (g == 0) red[wr][colbase + 16 * (i)] = u; }
      FOR16(CP)
    }
    __syncthreads();
    // col update
    if (tid < GP) {
      float cs = red[0][tid] + red[1][tid] + red[2][tid] + red[3][tid] +
                 red[4][tid] + red[5][tid] + red[6][tid] + red[7][tid];
      float uj = cs * Zinv + 1e-12f * Sr;
      float cj = c_s[tid];
      c_s[tid] = mp_sh[tid] ? (cj / (cj * uj + 1e-12f)) : 0.f;
    }
    __syncthreads();
    if (wid == 0) {  // Sc
      float v = c_s[lane] + c_s[lane + 64] + c_s[lane + 128] + c_s[lane + 192] +
                c_s[lane + 256] + c_s[lane + 320] + c_s[lane + 384] + c_s[lane + 448];
      #pragma unroll
      for (int m = 1; m <= 32; m <<= 1) v += __shfl_xor(v, m, 64);
      if (lane == 0) sc_sh = v;
    }
    __syncthreads();
    Sc = sc_sh;
    if (it < 3) {  // row pass for next iteration
      float qa0 = 0.f, qa1 = 0.f, qa2 = 0.f, qa3 = 0.f;
#define RP(i) { float cv = c_s[colbase + 16 * (i)]; \
      qa0 += P##i[0] * cv; qa1 += P##i[1] * cv; qa2 += P##i[2] * cv; qa3 += P##i[3] * cv; }
      FOR16(RP)
      #pragma unroll
      for (int m = 1; m <= 8; m <<= 1) {
        qa0 += __shfl_xor(qa0, m, 64); qa1 += __shfl_xor(qa1, m, 64);
        qa2 += __shfl_xor(qa2, m, 64); qa3 += __shfl_xor(qa3, m, 64);
      }
      if (c15 == 0) t2[ch][row0 + 0] = qa0;
      if (c15 == 1) t2[ch][row0 + 1] = qa1;
      if (c15 == 2) t2[ch][row0 + 2] = qa2;
      if (c15 == 3) t2[ch][row0 + 3] = qa3;
      __syncthreads();
      if (tid < GD) t_s[tid] = t2[0][tid] + t2[1][tid];
    }
  }

  // ---- tiny output: r, c, Zinv
  size_t rb = (size_t)(n * 8 + h) * 1024;
  if (tid < GD) rcz[rb + tid] = r_s[tid];
  if (tid < GP) rcz[rb + 128 + tid] = c_s[tid];
  if (tid == 0) rcz[rb + 640] = Zinv;
}

// ============ k4: A writer (blocks 0..511) + query_embed (512..639) ==========
extern "C" __global__ __launch_bounds__(256)
void k_write_embed(const short* __restrict__ qd, const short* __restrict__ kp,
                   const float* __restrict__ rcz,
                   const float* __restrict__ part, const int* __restrict__ cntp,
                   const float* __restrict__ Wvp, const float* __restrict__ Wvd,
                   float* __restrict__ out) {
  int bid = blockIdx.x;
  int t = threadIdx.x;
  if (bid >= 512) {  // ---- embed: 0.5*(sp@Wvp^T + sd@Wvd^T)/cnt ----
    int bb = bid - 512;
    int n = bb >> 3;
    int dchunk = (bb & 7) * 32;
    __shared__ float sps[256], sds[256];
    float a1 = 0.f;
    #pragma unroll
    for (int i = 0; i < 32; ++i) a1 += part[(size_t)(n * 32 + i) * 256 + t];
    sps[t] = a1;
    float a2 = 0.f;
    #pragma unroll
    for (int i = 0; i < 8; ++i) a2 += part[(size_t)(512 + n * 8 + i) * 256 + t];
    sds[t] = a2;
    __syncthreads();
    int cp = 0, cd = 0;
    #pragma unroll
    for (int i = 0; i < 32; ++i) cp += cntp[n * 32 + i];
    #pragma unroll
    for (int i = 0; i < 8; ++i) cd += cntp[512 + n * 8 + i];
    int dloc = t >> 3, ks = (t & 7) * 32;
    int d = dchunk + dloc;
    const float* wp = Wvp + (size_t)d * 256 + ks;
    const float* wd = Wvd + (size_t)d * 256 + ks;
    float acc = 0.f;
    #pragma unroll
    for (int k = 0; k < 32; k += 4) {
      float4 a = *(const float4*)(wp + k);
      float4 c = *(const float4*)(wd + k);
      acc += sps[ks + k] * a.x + sps[ks + k + 1] * a.y + sps[ks + k + 2] * a.z + sps[ks + k + 3] * a.w
           + sds[ks + k] * c.x + sds[ks + k + 1] * c.y + sds[ks + k + 2] * c.z + sds[ks + k + 3] * c.w;
    }
    #pragma unroll
    for (int m = 1; m <= 4; m <<= 1) acc += __shfl_xor(acc, m, 64);
    if ((t & 7) == 0) {
      acc *= 0.5f;
      out[n * 512 + d]       = acc / (float)cp;
      out[n * 512 + 256 + d] = acc / (float)cd;
    }
    return;
  }
  // ---- A writer: recompute P in f32, apply r/c/Zinv; h-contiguous stores ----
  int n = ((bid & 7) << 1) | ((bid >> 3) & 1);
  int rest = bid >> 4;
  int rt = rest >> 2;            // row tile (16 rows)
  int cc = rest & 3;             // col chunk (128 cols)
  int w = t >> 6, lane = t & 63;
  int c15 = lane & 15, g = lane >> 4;

  const short* qbase = qd + ((size_t)(n * GD + rt * 16 + c15)) * 256;
  bf16x8 af[8];
  #pragma unroll
  for (int h = 0; h < 8; ++h) af[h] = *(const bf16x8*)(qbase + h * HDT + g * 8);

  size_t rb = (size_t)n * 8 * 1024;
  float rv[8][4], zin[8];
  #pragma unroll
  for (int h = 0; h < 8; ++h) {
    const float* rp = rcz + rb + (size_t)h * 1024;
    #pragma unroll
    for (int r = 0; r < 4; ++r) rv[h][r] = rp[rt * 16 + 4 * g + r];
    zin[h] = rp[640];
  }

  #pragma unroll
  for (int ct = 0; ct < 2; ++ct) {
    int col = cc * 128 + w * 32 + ct * 16 + c15;
    f32x4 acc[8]; float cw[8];
    #pragma unroll
    for (int h = 0; h < 8; ++h) {
      bf16x8 bfr = *(const bf16x8*)(kp + ((size_t)(n * GP + col)) * 256 + h * HDT + g * 8);
      acc[h] = __builtin_amdgcn_mfma_f32_16x16x32_bf16(af[h], bfr, (f32x4){0.f,0.f,0.f,0.f}, 0, 0, 0);
      cw[h] = rcz[rb + (size_t)h * 1024 + 128 + col];
    }
    #pragma unroll
    for (int r = 0; r < 4; ++r) {
      int row = rt * 16 + 4 * g + r;
      float4 lo, hi;
      lo.x = rv[0][r] * (__expf(acc[0][r] * SCL) * zin[0] + 1e-12f) * cw[0];
      lo.y = rv[1][r] * (__expf(acc[1][r] * SCL) * zin[1] + 1e-12f) * cw[1];
      lo.z = rv[2][r] * (__expf(acc[2][r] * SCL) * zin[2] + 1e-12f) * cw[2];
      lo.w = rv[3][r] * (__expf(acc[3][r] * SCL) * zin[3] + 1e-12f) * cw[3];
      hi.x = rv[4][r] * (__expf(acc[4][r] * SCL) * zin[4] + 1e-12f) * cw[4];
      hi.y = rv[5][r] * (__expf(acc[5][r] * SCL) * zin[5] + 1e-12f) * cw[5];
      hi.z = rv[6][r] * (__expf(acc[6][r] * SCL) * zin[6] + 1e-12f) * cw[6];
      hi.w = rv[7][r] * (__expf(acc[7][r] * SCL) * zin[7] + 1e-12f) * cw[7];
      float* dst = out + 8192 + (((size_t)(n * GD + row)) * GP + col) * 8;
      *(float4*)dst = lo;
      *(float4*)(dst + 4) = hi;
    }
  }
}

extern "C" void kernel_launch(void* const* d_in, const int* in_sizes, int n_in,
                              void* d_out, int out_size, void* d_ws, size_t ws_size,
                              hipStream_t stream) {
  const float* protein = (const float*)d_in[0];
  const float* drug    = (const float*)d_in[1];
  const int*   mprot   = (const int*)d_in[2];
  const int*   mdrug   = (const int*)d_in[3];
  const float* Wk_p = (const float*)d_in[5];
  const float* Wv_p = (const float*)d_in[6];
  const float* Wq_d = (const float*)d_in[7];
  const float* Wv_d = (const float*)d_in[9];
  float* out = (float*)d_out;

  char* wsb = (char*)d_ws;
  short* pg_bf = (short*)wsb;                 wsb += (size_t)NB * GP * 256 * 2;  // 4 MB
  short* dg_bf = (short*)wsb;                 wsb += (size_t)NB * GD * 256 * 2;  // 1 MB
  short* kp_bf = (short*)wsb;                 wsb += (size_t)NB * GP * 256 * 2;  // 4 MB
  short* qd_bf = (short*)wsb;                 wsb += (size_t)NB * GD * 256 * 2;  // 1 MB
  short* Wk_bf = (short*)wsb;                 wsb += 65536 * 2;
  short* Wq_bf = (short*)wsb;                 wsb += 65536 * 2;
  float* part  = (float*)wsb;                 wsb += (size_t)640 * 256 * 4;      // 640 KB
  float* rcz   = (float*)wsb;                 wsb += (size_t)128 * 1024 * 4;     // 512 KB
  int*   cntp  = (int*)wsb;                   wsb += 640 * 4;
  int*   mp_g  = (int*)wsb;                   wsb += 8192 * 4;
  int*   md_g  = (int*)wsb;                   wsb += 2048 * 4;

  k_group<<<704, 256, 0, stream>>>(protein, drug, mprot, mdrug, Wk_p, Wq_d,
                                   pg_bf, dg_bf, mp_g, md_g, Wk_bf, Wq_bf,
                                   part, cntp);
  k_projbf<<<320, 256, 0, stream>>>(pg_bf, dg_bf, Wk_bf, Wq_bf, kp_bf, qd_bf);
  k_scalars<<<128, 1024, 0, stream>>>(qd_bf, kp_bf, md_g, mp_g, rcz);
  k_write_embed<<<640, 256, 0, stream>>>(qd_bf, kp_bf, rcz, part, cntp,
                                         Wv_p, Wv_d, out);
}

// Round 7
// 158.688 us; speedup vs baseline: 1.8032x; 1.0281x over previous
//
#include <hip/hip_runtime.h>
#include <hip/hip_bf16.h>

// Sizes (fixed by the problem)
#define NB   16      // batch
#define DT   256     // model dim
#define HT   8       // heads
#define HDT  32      // head dim
#define GP   512     // protein groups (2048/4)
#define GD   128     // drug groups (512/4)
#define SCL  0.17677669529663687f

using bf16x8 = __attribute__((ext_vector_type(8))) short;
using bf16x4 = __attribute__((ext_vector_type(4))) short;
using f32x4  = __attribute__((ext_vector_type(4))) float;
using h16x4  = __attribute__((ext_vector_type(4))) _Float16;

__device__ __forceinline__ short f2bf(float f) {
  __hip_bfloat16 h = __float2bfloat16(f);
  short s; __builtin_memcpy(&s, &h, 2);
  return s;
}

__device__ __forceinline__ bf16x8 cvt8(float4 a, float4 b) {
  bf16x8 r;
  r[0] = f2bf(a.x); r[1] = f2bf(a.y); r[2] = f2bf(a.z); r[3] = f2bf(a.w);
  r[4] = f2bf(b.x); r[5] = f2bf(b.y); r[6] = f2bf(b.z); r[7] = f2bf(b.w);
  return r;
}

// ============ k1: grouping (f32 -> grouped bf16) + masks + part sums + W cvt
// blocks 0..511: protein, 16 groups each; 512..639: drug; 640..703: W cvt.
extern "C" __global__ __launch_bounds__(256)
void k_group(const float* __restrict__ protein, const float* __restrict__ drug,
             const int* __restrict__ mprot, const int* __restrict__ mdrug,
             const float* __restrict__ Wk, const float* __restrict__ Wq,
             short* __restrict__ pg_bf, short* __restrict__ dg_bf,
             int* __restrict__ mp_g, int* __restrict__ md_g,
             short* __restrict__ Wk_bf, short* __restrict__ Wq_bf,
             float* __restrict__ part, int* __restrict__ cntp) {
  int b = blockIdx.x, t = threadIdx.x;
  if (b >= 640) {  // ---- W conversion ----
    int idx = (b - 640) * 2048 + t * 8;
    const float* s; short* d;
    if (idx < 65536) { s = Wk + idx; d = Wk_bf + idx; }
    else             { s = Wq + (idx - 65536); d = Wq_bf + (idx - 65536); }
    *(bf16x8*)d = cvt8(*(const float4*)s, *(const float4*)(s + 4));
    return;
  }
  const float* src; const int* msk; short* dst; int* mg; int gbase;
  if (b < 512) { src = protein; msk = mprot; dst = pg_bf; mg = mp_g; gbase = b * 16; }
  else         { src = drug;    msk = mdrug; dst = dg_bf; mg = md_g; gbase = (b - 512) * 16; }

  __shared__ int gm_s[16];
  __shared__ float part_s[4][256];
  if (t < 16) {
    const int* m = msk + (size_t)(gbase + t) * 4;
    int v = (m[0] | m[1] | m[2] | m[3]) ? 1 : 0;
    gm_s[t] = v;
    mg[gbase + t] = v;
  }
  __syncthreads();
  if (t == 0) {
    int c = 0;
    #pragma unroll
    for (int i = 0; i < 16; ++i) c += gm_s[i];
    cntp[b] = c;
  }

  int col4 = t & 63, gsub = t >> 6;
  float a0 = 0.f, a1 = 0.f, a2 = 0.f, a3 = 0.f;
  #pragma unroll
  for (int it = 0; it < 4; ++it) {
    int grp = gbase + gsub + it * 4;
    const float* rp = src + (size_t)grp * 1024 + col4 * 4;
    float4 r0 = *(const float4*)rp;
    float4 r1 = *(const float4*)(rp + 256);
    float4 r2 = *(const float4*)(rp + 512);
    float4 r3 = *(const float4*)(rp + 768);
    float m0 = 0.25f * (r0.x + r1.x + r2.x + r3.x);
    float m1 = 0.25f * (r0.y + r1.y + r2.y + r3.y);
    float m2 = 0.25f * (r0.z + r1.z + r2.z + r3.z);
    float m3 = 0.25f * (r0.w + r1.w + r2.w + r3.w);
    bf16x4 v; v[0] = f2bf(m0); v[1] = f2bf(m1); v[2] = f2bf(m2); v[3] = f2bf(m3);
    *(bf16x4*)(dst + (size_t)grp * 256 + col4 * 4) = v;
    if (gm_s[gsub + it * 4]) { a0 += m0; a1 += m1; a2 += m2; a3 += m3; }
  }
  part_s[gsub][col4 * 4 + 0] = a0;
  part_s[gsub][col4 * 4 + 1] = a1;
  part_s[gsub][col4 * 4 + 2] = a2;
  part_s[gsub][col4 * 4 + 3] = a3;
  __syncthreads();
  part[(size_t)b * 256 + t] = part_s[0][t] + part_s[1][t] + part_s[2][t] + part_s[3][t];
}

// ============ k2: bf16 projection GEMM + query_embed ========================
// blocks 0..255: kp; 256..319: qd; 320..447: embed.
extern "C" __global__ __launch_bounds__(256)
void k_projbf(const short* __restrict__ pg_bf, const short* __restrict__ dg_bf,
              const short* __restrict__ Wk_bf, const short* __restrict__ Wq_bf,
              short* __restrict__ kp_bf, short* __restrict__ qd_bf,
              const float* __restrict__ part, const int* __restrict__ cntp,
              const float* __restrict__ Wvp, const float* __restrict__ Wvd,
              float* __restrict__ out) {
  int b = blockIdx.x, t = threadIdx.x;
  if (b >= 320) {  // ---- embed: 0.5*(sp@Wvp^T + sd@Wvd^T)/cnt ----
    int bb = b - 320;
    int n = bb >> 3;
    int dchunk = (bb & 7) * 32;
    __shared__ float sps[256], sds[256];
    float a1 = 0.f;
    #pragma unroll
    for (int i = 0; i < 32; ++i) a1 += part[(size_t)(n * 32 + i) * 256 + t];
    sps[t] = a1;
    float a2 = 0.f;
    #pragma unroll
    for (int i = 0; i < 8; ++i) a2 += part[(size_t)(512 + n * 8 + i) * 256 + t];
    sds[t] = a2;
    __syncthreads();
    int cp = 0, cd = 0;
    #pragma unroll
    for (int i = 0; i < 32; ++i) cp += cntp[n * 32 + i];
    #pragma unroll
    for (int i = 0; i < 8; ++i) cd += cntp[512 + n * 8 + i];
    int dloc = t >> 3, ks = (t & 7) * 32;
    int d = dchunk + dloc;
    const float* wp = Wvp + (size_t)d * 256 + ks;
    const float* wd = Wvd + (size_t)d * 256 + ks;
    float acc = 0.f;
    #pragma unroll
    for (int k = 0; k < 32; k += 4) {
      float4 a = *(const float4*)(wp + k);
      float4 c = *(const float4*)(wd + k);
      acc += sps[ks + k] * a.x + sps[ks + k + 1] * a.y + sps[ks + k + 2] * a.z + sps[ks + k + 3] * a.w
           + sds[ks + k] * c.x + sds[ks + k + 1] * c.y + sds[ks + k + 2] * c.z + sds[ks + k + 3] * c.w;
    }
    #pragma unroll
    for (int m = 1; m <= 4; m <<= 1) acc += __shfl_xor(acc, m, 64);
    if ((t & 7) == 0) {
      acc *= 0.5f;
      out[n * 512 + d]       = acc / (float)cp;
      out[n * 512 + 256 + d] = acc / (float)cd;
    }
    return;
  }
  // ---- projection ----
  int w = t >> 6, lane = t & 63, c15 = lane & 15, g = lane >> 4;
  const short *A, *W; short* o; int rowbase;
  if (b < 256) { A = pg_bf; W = Wk_bf; o = kp_bf; rowbase = b * 32; }
  else         { A = dg_bf; W = Wq_bf; o = qd_bf; rowbase = (b - 256) * 32; }
  int rt = rowbase + (w & 1) * 16;
  int ch = (w >> 1) * 128;

  const short* ap = A + (size_t)(rt + c15) * 256;
  f32x4 acc[8];
  #pragma unroll
  for (int i = 0; i < 8; ++i) acc[i] = (f32x4){0.f, 0.f, 0.f, 0.f};

  #pragma unroll
  for (int ks = 0; ks < 8; ++ks) {
    bf16x8 af = *(const bf16x8*)(ap + ks * 32 + g * 8);
    #pragma unroll
    for (int ct = 0; ct < 8; ++ct) {
      bf16x8 bfr = *(const bf16x8*)(W + (size_t)(ch + ct * 16 + c15) * 256 + ks * 32 + g * 8);
      acc[ct] = __builtin_amdgcn_mfma_f32_16x16x32_bf16(af, bfr, acc[ct], 0, 0, 0);
    }
  }
  #pragma unroll
  for (int ct = 0; ct < 8; ++ct) {
    #pragma unroll
    for (int r = 0; r < 4; ++r) {
      o[(size_t)(rt + 4 * g + r) * 256 + ch + ct * 16 + c15] = f2bf(acc[ct][r]);
    }
  }
}

// ============ k3: dp sinkhorn scalars, f16 named-reg P, merged barriers =====
// One block per (n,h); 16 waves: wr row-group (16 rows), ch col-half.
// Butterfly reductions leave the sum in ALL lanes -> Sr/Sc/Z/Kv computed
// redundantly per wave, no wave0+broadcast barriers.
#define FOR16(X) X(0) X(1) X(2) X(3) X(4) X(5) X(6) X(7) X(8) X(9) X(10) X(11) X(12) X(13) X(14) X(15)

extern "C" __global__ __launch_bounds__(1024)
void k_scalars(const short* __restrict__ qd, const short* __restrict__ kp,
               const int* __restrict__ md_g, const int* __restrict__ mp_g,
               float* __restrict__ rcz) {
  int bid = blockIdx.x;
  int n = ((bid & 7) << 1) | ((bid >> 3) & 1);   // XCD swizzle
  int h = bid >> 4;
  int tid = threadIdx.x;
  int wid = tid >> 6, lane = tid & 63;
  int wr = wid >> 1, ch = wid & 1;
  int c15 = lane & 15, g = lane >> 4;

  __shared__ float c_s[GP];
  __shared__ float r_s[GD];
  __shared__ float t2[2][GD];
  __shared__ float red[8][GP];
  __shared__ int mp_sh[GP];
  __shared__ int md_sh[GD];

  if (tid < GP) { int m = mp_g[n * GP + tid]; mp_sh[tid] = m; c_s[tid] = m ? 1.f : 0.f; }
  if (tid < GD) { int m = md_g[n * GD + tid]; md_sh[tid] = m; r_s[tid] = m ? 1.f : 0.f; }
  __syncthreads();

  // Kv redundant per wave (butterfly -> all lanes)
  float kv;
  {
    float v = (float)(mp_sh[lane] + mp_sh[lane + 64] + mp_sh[lane + 128] + mp_sh[lane + 192] +
                      mp_sh[lane + 256] + mp_sh[lane + 320] + mp_sh[lane + 384] + mp_sh[lane + 448]);
    #pragma unroll
    for (int m = 1; m <= 32; m <<= 1) v += __shfl_xor(v, m, 64);
    kv = v;
  }

  // ---- logits via MFMA, P = exp(masked logit) in named f16x4 regs (32 VGPR)
  int qrow = 16 * wr + c15;
  bf16x8 af = *(const bf16x8*)(qd + ((size_t)(n * GD + qrow)) * 256 + h * HDT + g * 8);
  int row0 = 16 * wr + 4 * g;
  int mr0 = md_sh[row0], mr1 = md_sh[row0 + 1], mr2 = md_sh[row0 + 2], mr3 = md_sh[row0 + 3];
  const short* kbase = kp + ((size_t)n * GP) * 256 + h * HDT + g * 8;
  int colbase = ch * 256 + c15;

#define DECLP(i) h16x4 P##i;
  FOR16(DECLP)
#define MKP(i) { int col = colbase + 16 * (i); \
    bf16x8 bfr = *(const bf16x8*)(kbase + (size_t)col * 256); \
    f32x4 a = __builtin_amdgcn_mfma_f32_16x16x32_bf16(af, bfr, (f32x4){0.f,0.f,0.f,0.f}, 0, 0, 0); \
    int mc = mp_sh[col]; \
    P##i[0] = (_Float16)((mc && mr0) ? __expf(a[0] * SCL) : 0.f); \
    P##i[1] = (_Float16)((mc && mr1) ? __expf(a[1] * SCL) : 0.f); \
    P##i[2] = (_Float16)((mc && mr2) ? __expf(a[2] * SCL) : 0.f); \
    P##i[3] = (_Float16)((mc && mr3) ? __expf(a[3] * SCL) : 0.f); }
  FOR16(MKP)

  // ---- initial row sums -> t2
  {
    float pa0 = 0.f, pa1 = 0.f, pa2 = 0.f, pa3 = 0.f;
#define RS0(i) pa0 += (float)P##i[0]; pa1 += (float)P##i[1]; pa2 += (float)P##i[2]; pa3 += (float)P##i[3];
    FOR16(RS0)
    #pragma unroll
    for (int m = 1; m <= 8; m <<= 1) {
      pa0 += __shfl_xor(pa0, m, 64); pa1 += __shfl_xor(pa1, m, 64);
      pa2 += __shfl_xor(pa2, m, 64); pa3 += __shfl_xor(pa3, m, 64);
    }
    if (c15 == 0) t2[ch][row0 + 0] = pa0;
    if (c15 == 1) t2[ch][row0 + 1] = pa1;
    if (c15 == 2) t2[ch][row0 + 2] = pa2;
    if (c15 == 3) t2[ch][row0 + 3] = pa3;
  }
  __syncthreads();
  // Z redundant per wave
  float Zinv;
  {
    float v = t2[0][lane] + t2[1][lane] + t2[0][lane + 64] + t2[1][lane + 64];
    #pragma unroll
    for (int m = 1; m <= 32; m <<= 1) v += __shfl_xor(v, m, 64);
    Zinv = 1.0f / v;
  }
  float Sc = kv;

  #pragma unroll 1
  for (int it = 0; it < 4; ++it) {
    // row update (waves 0-1)
    if (tid < GD) {
      float ti = (t2[0][tid] + t2[1][tid]) * Zinv + 1e-12f * Sc;
      float ri = r_s[tid];
      r_s[tid] = md_sh[tid] ? (ri / (ri * ti + 1e-12f)) : 0.f;
    }
    __syncthreads();
    // Sr redundant per wave + col pass
    float Sr;
    {
      float v = r_s[lane] + r_s[lane + 64];
      #pragma unroll
      for (int m = 1; m <= 32; m <<= 1) v += __shfl_xor(v, m, 64);
      Sr = v;
    }
    {
      float rr0 = r_s[row0], rr1 = r_s[row0 + 1], rr2 = r_s[row0 + 2], rr3 = r_s[row0 + 3];
#define CP(i) { float u = (float)P##i[0] * rr0 + (float)P##i[1] * rr1 + \
                         (float)P##i[2] * rr2 + (float)P##i[3] * rr3; \
      u += __shfl_xor(u, 16, 64); u += __shfl_xor(u, 32, 64); \
      if (g == 0) red[wr][colbase + 16 * (i)] = u; }
      FOR16(CP)
    }
    __syncthreads();
    // col update (waves 0-7)
    if (tid < GP) {
      float cs = red[0][tid] + red[1][tid] + red[2][tid] + red[3][tid] +
                 red[4][tid] + red[5][tid] + red[6][tid] + red[7][tid];
      float uj = cs * Zinv + 1e-12f * Sr;
      float cj = c_s[tid];
      c_s[tid] = mp_sh[tid] ? (cj / (cj * uj + 1e-12f)) : 0.f;
    }
    __syncthreads();
    if (it < 3) {
      // Sc redundant per wave + row pass
      {
        float v = c_s[lane] + c_s[lane + 64] + c_s[lane + 128] + c_s[lane + 192] +
                  c_s[lane + 256] + c_s[lane + 320] + c_s[lane + 384] + c_s[lane + 448];
        #pragma unroll
        for (int m = 1; m <= 32; m <<= 1) v += __shfl_xor(v, m, 64);
        Sc = v;
      }
      float qa0 = 0.f, qa1 = 0.f, qa2 = 0.f, qa3 = 0.f;
#define RP(i) { float cv = c_s[colbase + 16 * (i)]; \
      qa0 += (float)P##i[0] * cv; qa1 += (float)P##i[1] * cv; \
      qa2 += (float)P##i[2] * cv; qa3 += (float)P##i[3] * cv; }
      FOR16(RP)
      #pragma unroll
      for (int m = 1; m <= 8; m <<= 1) {
        qa0 += __shfl_xor(qa0, m, 64); qa1 += __shfl_xor(qa1, m, 64);
        qa2 += __shfl_xor(qa2, m, 64); qa3 += __shfl_xor(qa3, m, 64);
      }
      if (c15 == 0) t2[ch][row0 + 0] = qa0;
      if (c15 == 1) t2[ch][row0 + 1] = qa1;
      if (c15 == 2) t2[ch][row0 + 2] = qa2;
      if (c15 == 3) t2[ch][row0 + 3] = qa3;
      __syncthreads();
    }
  }

  // ---- tiny output: r, c, Zinv
  size_t rb = (size_t)(n * 8 + h) * 1024;
  if (tid < GD) rcz[rb + tid] = r_s[tid];
  if (tid < GP) rcz[rb + 128 + tid] = c_s[tid];
  if (tid == 0) rcz[rb + 640] = Zinv;
}

// ============ k4: A writer, LDS-staged kp tile (swizzled), coalesced stores ==
// grid 512 = (n,16-row tile,128-col chunk); h inner -> 2 float4 stores/cell-row.
extern "C" __global__ __launch_bounds__(256)
void k_write(const short* __restrict__ qd, const short* __restrict__ kp,
             const float* __restrict__ rcz, float* __restrict__ out) {
  int bid = blockIdx.x;
  int n = ((bid & 7) << 1) | ((bid >> 3) & 1);
  int rest = bid >> 4;
  int rt = rest >> 2;            // row tile (16 rows)
  int cc = rest & 3;             // col chunk (128 cols)
  int t = threadIdx.x;
  int w = t >> 6, lane = t & 63;
  int c15 = lane & 15, g = lane >> 4;

  __shared__ short ktile[32768];   // 64 KB: 128 cols x 256 d, XOR-swizzled

  // stage kp[cc*128 .. +128)[0..256) coalesced; swizzle db ^= (col&7)<<4
  const short* kpsrc = kp + ((size_t)(n * GP + cc * 128)) * 256;
  #pragma unroll
  for (int j = 0; j < 16; ++j) {
    int flatb = j * 4096 + t * 16;          // byte offset in linear tile
    int col = flatb >> 9, db = flatb & 511;
    bf16x8 v = *(const bf16x8*)(kpsrc + ((size_t)col << 8) + (db >> 1));
    *(bf16x8*)&ktile[(col * 512 + (db ^ ((col & 7) << 4))) >> 1] = v;
  }

  const short* qbase = qd + ((size_t)(n * GD + rt * 16 + c15)) * 256;
  bf16x8 af[8];
  #pragma unroll
  for (int h = 0; h < 8; ++h) af[h] = *(const bf16x8*)(qbase + h * HDT + g * 8);

  size_t rb = (size_t)n * 8 * 1024;
  float rv[8][4], zin[8];
  #pragma unroll
  for (int h = 0; h < 8; ++h) {
    const float* rp = rcz + rb + (size_t)h * 1024;
    #pragma unroll
    for (int r = 0; r < 4; ++r) rv[h][r] = rp[rt * 16 + 4 * g + r];
    zin[h] = rp[640];
  }
  __syncthreads();

  #pragma unroll
  for (int ct = 0; ct < 2; ++ct) {
    int lc = w * 32 + ct * 16 + c15;        // local col in tile
    int col = cc * 128 + lc;
    f32x4 acc[8]; float cw[8];
    #pragma unroll
    for (int h = 0; h < 8; ++h) {
      int db = (h * 64 + g * 16) ^ ((lc & 7) << 4);
      bf16x8 bfr = *(const bf16x8*)&ktile[(lc * 512 + db) >> 1];
      acc[h] = __builtin_amdgcn_mfma_f32_16x16x32_bf16(af[h], bfr, (f32x4){0.f,0.f,0.f,0.f}, 0, 0, 0);
      cw[h] = rcz[rb + (size_t)h * 1024 + 128 + col];
    }
    #pragma unroll
    for (int r = 0; r < 4; ++r) {
      int row = rt * 16 + 4 * g + r;
      float4 lo, hi;
      lo.x = rv[0][r] * (__expf(acc[0][r] * SCL) * zin[0] + 1e-12f) * cw[0];
      lo.y = rv[1][r] * (__expf(acc[1][r] * SCL) * zin[1] + 1e-12f) * cw[1];
      lo.z = rv[2][r] * (__expf(acc[2][r] * SCL) * zin[2] + 1e-12f) * cw[2];
      lo.w = rv[3][r] * (__expf(acc[3][r] * SCL) * zin[3] + 1e-12f) * cw[3];
      hi.x = rv[4][r] * (__expf(acc[4][r] * SCL) * zin[4] + 1e-12f) * cw[4];
      hi.y = rv[5][r] * (__expf(acc[5][r] * SCL) * zin[5] + 1e-12f) * cw[5];
      hi.z = rv[6][r] * (__expf(acc[6][r] * SCL) * zin[6] + 1e-12f) * cw[6];
      hi.w = rv[7][r] * (__expf(acc[7][r] * SCL) * zin[7] + 1e-12f) * cw[7];
      float* dst = out + 8192 + (((size_t)(n * GD + row)) * GP + col) * 8;
      *(float4*)dst = lo;
      *(float4*)(dst + 4) = hi;
    }
  }
}

extern "C" void kernel_launch(void* const* d_in, const int* in_sizes, int n_in,
                              void* d_out, int out_size, void* d_ws, size_t ws_size,
                              hipStream_t stream) {
  const float* protein = (const float*)d_in[0];
  const float* drug    = (const float*)d_in[1];
  const int*   mprot   = (const int*)d_in[2];
  const int*   mdrug   = (const int*)d_in[3];
  const float* Wk_p = (const float*)d_in[5];
  const float* Wv_p = (const float*)d_in[6];
  const float* Wq_d = (const float*)d_in[7];
  const float* Wv_d = (const float*)d_in[9];
  float* out = (float*)d_out;

  char* wsb = (char*)d_ws;
  short* pg_bf = (short*)wsb;                 wsb += (size_t)NB * GP * 256 * 2;  // 4 MB
  short* dg_bf = (short*)wsb;                 wsb += (size_t)NB * GD * 256 * 2;  // 1 MB
  short* kp_bf = (short*)wsb;                 wsb += (size_t)NB * GP * 256 * 2;  // 4 MB
  short* qd_bf = (short*)wsb;                 wsb += (size_t)NB * GD * 256 * 2;  // 1 MB
  short* Wk_bf = (short*)wsb;                 wsb += 65536 * 2;
  short* Wq_bf = (short*)wsb;                 wsb += 65536 * 2;
  float* part  = (float*)wsb;                 wsb += (size_t)640 * 256 * 4;      // 640 KB
  float* rcz   = (float*)wsb;                 wsb += (size_t)128 * 1024 * 4;     // 512 KB
  int*   cntp  = (int*)wsb;                   wsb += 640 * 4;
  int*   mp_g  = (int*)wsb;                   wsb += 8192 * 4;
  int*   md_g  = (int*)wsb;                   wsb += 2048 * 4;

  k_group<<<704, 256, 0, stream>>>(protein, drug, mprot, mdrug, Wk_p, Wq_d,
                                   pg_bf, dg_bf, mp_g, md_g, Wk_bf, Wq_bf,
                                   part, cntp);
  k_projbf<<<448, 256, 0, stream>>>(pg_bf, dg_bf, Wk_bf, Wq_bf, kp_bf, qd_bf,
                                    part, cntp, Wv_p, Wv_d, out);
  k_scalars<<<128, 1024, 0, stream>>>(qd_bf, kp_bf, md_g, mp_g, rcz);
  k_write<<<512, 256, 0, stream>>>(qd_bf, kp_bf, rcz, out);
}